// Round 1
// 905.510 us; speedup vs baseline: 1.1062x; 1.1062x over previous
//
#include <hip/hip_runtime.h>
#include <hip/hip_bf16.h>
#include <cstdint>
#include <cstddef>

#define KEYSHIFT 20
#define COLMASK 0xFFFFFu
#define EPB 8192    // edges per count/scatter block (1024 threads x 8)
#define SUB 4096    // staged sub-chunk inside scatter (fits 54KB LDS)
#define BSHIFT 8    // 256 rows per bucket
#define NRB 256     // rows per bucket (1 << BSHIFT)
#define CCAP 3072   // LDS sort capacity per bucket (avg ~2560, max ~2750)

// ---------------------------------------------------------------------------
// Host-side reproduction of np.random.RandomState(2).permutation(64):
// MT19937 init_genrand(2), Fisher-Yates with numpy random_interval
// (mask+rejection). Mask bit d = (perm[d] >= 38).
// ---------------------------------------------------------------------------
static uint64_t compute_mask_bits() {
    uint32_t mt[624];
    mt[0] = 2u;
    for (int i = 1; i < 624; i++)
        mt[i] = 1812433253u * (mt[i - 1] ^ (mt[i - 1] >> 30)) + (uint32_t)i;
    int mti = 624;
    auto genrand = [&]() -> uint32_t {
        if (mti >= 624) {
            for (int k = 0; k < 624; k++) {
                uint32_t y = (mt[k] & 0x80000000u) | (mt[(k + 1) % 624] & 0x7fffffffu);
                mt[k] = mt[(k + 397) % 624] ^ (y >> 1) ^ ((y & 1u) ? 2567483615u : 0u);
            }
            mti = 0;
        }
        uint32_t y = mt[mti++];
        y ^= y >> 11;
        y ^= (y << 7) & 2636928640u;
        y ^= (y << 15) & 4022730752u;
        y ^= y >> 18;
        return y;
    };
    int arr[64];
    for (int i = 0; i < 64; i++) arr[i] = i;
    for (int i = 63; i >= 1; i--) {
        uint32_t mask = (uint32_t)i;
        mask |= mask >> 1; mask |= mask >> 2; mask |= mask >> 4;
        mask |= mask >> 8; mask |= mask >> 16;
        uint32_t v;
        do { v = genrand() & mask; } while (v > (uint32_t)i);
        int tmp = arr[i]; arr[i] = arr[v]; arr[v] = tmp;
    }
    uint64_t bits = 0;
    for (int d = 0; d < 64; d++)
        if (arr[d] >= 38) bits |= (1ull << d);
    return bits;
}

// ---------------------------------------------------------------------------
// Output-row flag set + compacted list (rows read by the final dot).
// ---------------------------------------------------------------------------
__global__ void flag_kernel(const int* __restrict__ users, const int* __restrict__ items,
                            unsigned char* __restrict__ flag, int B, int U) {
    int i = blockIdx.x * 256 + threadIdx.x;
    if (i < B) flag[users[i]] = 1;
    else if (i < 2 * B) flag[U + items[i - B]] = 1;
}

__global__ void flist_kernel(const unsigned char* __restrict__ flag,
                             int* __restrict__ flist, int* __restrict__ fcount, int n) {
    int i = blockIdx.x * 256 + threadIdx.x;
    if (i < n && flag[i]) {
        int p = atomicAdd(fcount, 1);
        flist[p] = i;
    }
}

// ---------------------------------------------------------------------------
// Per-rating constant c1[r][j] = b1[r][j] + sum_k e_r[k] * W1[r][64+k][j].
// ---------------------------------------------------------------------------
__global__ void c1_kernel(const float* __restrict__ rating_emb, const float* __restrict__ W1,
                          const float* __restrict__ b1, float* __restrict__ c1_all) {
    int r = blockIdx.x;
    int t = threadIdx.x;  // 64 threads
    const float* W1r = W1 + (size_t)r * (128 * 64);
    float acc = b1[r * 64 + t];
    for (int k = 0; k < 64; k++)
        acc += rating_emb[r * 64 + k] * W1r[(64 + k) * 64 + t];
    c1_all[r * 64 + t] = acc;
}

// ---------------------------------------------------------------------------
// Build pass A (batched over ratings): LDS histogram over K=ceil(N/256) row
// buckets, then ONE global atomicAdd per (block,bucket) to reserve a range.
// 256-row buckets cut reserve-atomics 4x vs 64-row (R7/R9 lesson: device
// atomics are ~32B write-through at the homed L2).
// ---------------------------------------------------------------------------
__global__ __launch_bounds__(1024) void bucket_count_kernel(
    const int* __restrict__ rows, int* __restrict__ gcnt,
    int* __restrict__ blockBase, int E, int K, int nb) {
    __shared__ int hist[2048];
    int r = blockIdx.y, blk = blockIdx.x, t = threadIdx.x;
    for (int i = t; i < K; i += 1024) hist[i] = 0;
    __syncthreads();
    size_t base = (size_t)r * E + (size_t)blk * EPB;
    int cnt = E - blk * EPB;
    if (cnt > EPB) cnt = EPB;
    for (int k = t; k < cnt; k += 1024)
        atomicAdd(&hist[rows[base + k] >> BSHIFT], 1);
    __syncthreads();
    for (int i = t; i < K; i += 1024) {
        int c = hist[i];
        int bb = (c > 0) ? atomicAdd(&gcnt[r * K + i], c) : 0;
        blockBase[((size_t)r * nb + blk) * K + i] = bb;
    }
}

// ---------------------------------------------------------------------------
// Exclusive scan of K bucket counts -> bptr[K+1] per rating (grid.x = R).
// Generic for K <= 2047.
// ---------------------------------------------------------------------------
__global__ void bucket_scan_kernel(const int* __restrict__ gcnt,
                                   int* __restrict__ bptr, int K) {
    __shared__ int sh[256];
    int r = blockIdx.x;
    int t = threadIdx.x;
    int base = t * 8;
    int v[8];
    int s = 0;
    #pragma unroll
    for (int j = 0; j < 8; j++) {
        int idx = base + j;
        v[j] = (idx < K) ? gcnt[r * K + idx] : 0;
        s += v[j];
    }
    sh[t] = s;
    __syncthreads();
    for (int off = 1; off < 256; off <<= 1) {
        int x = (t >= off) ? sh[t - off] : 0;
        __syncthreads();
        sh[t] += x;
        __syncthreads();
    }
    int run = sh[t] - s;
    #pragma unroll
    for (int j = 0; j < 8; j++) {
        int idx = base + j;
        if (idx <= K) bptr[r * (K + 1) + idx] = run;
        run += v[j];
    }
}

// ---------------------------------------------------------------------------
// Build pass B: LDS-STAGED scatter into bucket-grouped rec (K <= 512).
// R13 theory: the old direct-scatter's 8B writes hit 64 random lines per
// wave -> 3.25x HBM write amplification (130MB vs 40MB payload). Here each
// 4096-edge sub-chunk is histogrammed, scanned (Hillis-Steele in LDS),
// staged bucket-grouped in LDS with its final global address, then written
// out linearly: consecutive threads hit consecutive addresses in ~84B runs.
// Stride-parameterized: batched mode launches grid.y=R with real strides;
// fallback launches grid.y=1 with pre-offset pointers and strides 0.
// ---------------------------------------------------------------------------
__global__ __launch_bounds__(1024) void bucket_scatter_kernel(
    const int* __restrict__ rows, const int* __restrict__ cols,
    const float* __restrict__ vals, const int* __restrict__ bptr,
    const int* __restrict__ blockBase, uint2* __restrict__ rec,
    int E, int K, long long eStride, long long pStride,
    long long bbStride, long long rStride) {
    __shared__ uint2 staged[SUB];   // 32KB
    __shared__ int gaddr[SUB];      // 16KB final rec index per staged slot
    __shared__ int cursor[512];     // running global cursor per bucket
    __shared__ int lhist[512];      // per-subchunk count -> local base
    __shared__ int aux[512];        // scan scratch -> goff (=gbase-localbase)
    int r = blockIdx.y;
    const int* rows_r = rows + (size_t)r * eStride;
    const int* cols_r = cols + (size_t)r * eStride;
    const float* vals_r = vals + (size_t)r * eStride;
    const int* bptr_r = bptr + (size_t)r * pStride;
    const int* bb_r = blockBase + (size_t)r * bbStride;
    uint2* rec_r = rec + (size_t)r * rStride;
    int blk = blockIdx.x, t = threadIdx.x;
    if (t < 512)
        cursor[t] = (t < K) ? (bptr_r[t] + bb_r[(size_t)blk * K + t]) : 0;
    size_t base = (size_t)blk * EPB;
    int cnt = E - blk * EPB;
    if (cnt > EPB) cnt = EPB;
    for (int c0 = 0; c0 < cnt; c0 += SUB) {
        int scnt = cnt - c0;
        if (scnt > SUB) scnt = SUB;
        if (t < 512) lhist[t] = 0;
        __syncthreads();
        int bkt_[4], lpos_[4];
        uint2 rv_[4];
        #pragma unroll
        for (int q = 0; q < 4; q++) {
            int kk = (q << 10) + t;
            bkt_[q] = -1;
            if (kk < scnt) {
                size_t g = base + c0 + kk;
                int row = rows_r[g];
                int b = row >> BSHIFT;
                bkt_[q] = b;
                rv_[q] = make_uint2(((uint32_t)(row & (NRB - 1)) << KEYSHIFT) |
                                        (uint32_t)cols_r[g],
                                    __float_as_uint(vals_r[g]));
                lpos_[q] = atomicAdd(&lhist[b], 1);
            }
        }
        __syncthreads();
        // inclusive scan of lhist[0..511] (threads >=512 only hit syncs)
        int v = (t < 512) ? lhist[t] : 0;
        if (t < 512) aux[t] = v;
        __syncthreads();
        for (int off = 1; off < 512; off <<= 1) {
            int x = 0;
            if (t >= off && t < 512) x = aux[t - off];
            __syncthreads();
            if (t < 512) aux[t] += x;
            __syncthreads();
        }
        if (t < 512) {
            int ex = aux[t] - v;     // exclusive local base
            int gb = cursor[t];      // global base for this sub-chunk
            cursor[t] = gb + v;
            lhist[t] = ex;
            aux[t] = gb - ex;        // goff: gaddr = goff[b] + staged_idx
        }
        __syncthreads();
        #pragma unroll
        for (int q = 0; q < 4; q++) {
            if (bkt_[q] >= 0) {
                int sidx = lhist[bkt_[q]] + lpos_[q];
                staged[sidx] = rv_[q];
                gaddr[sidx] = aux[bkt_[q]] + sidx;
            }
        }
        __syncthreads();
        for (int i = t; i < scnt; i += 1024)
            rec_r[gaddr[i]] = staged[i];
        __syncthreads();
    }
}

// ---------------------------------------------------------------------------
// Build pass B legacy (direct scatter) — only used if K > 512.
// ---------------------------------------------------------------------------
__global__ __launch_bounds__(1024) void bucket_scatter_legacy(
    const int* __restrict__ rows, const int* __restrict__ cols,
    const float* __restrict__ vals, const int* __restrict__ bptr,
    const int* __restrict__ blockBase, uint2* __restrict__ rec,
    int E, int K, long long eStride, long long pStride,
    long long bbStride, long long rStride) {
    __shared__ int cursor[2048];
    int r = blockIdx.y;
    const int* rows_r = rows + (size_t)r * eStride;
    const int* cols_r = cols + (size_t)r * eStride;
    const float* vals_r = vals + (size_t)r * eStride;
    const int* bptr_r = bptr + (size_t)r * pStride;
    const int* bb_r = blockBase + (size_t)r * bbStride;
    uint2* rec_r = rec + (size_t)r * rStride;
    int blk = blockIdx.x, t = threadIdx.x;
    for (int i = t; i < K; i += 1024)
        cursor[i] = bptr_r[i] + bb_r[(size_t)blk * K + i];
    __syncthreads();
    size_t base = (size_t)blk * EPB;
    int cnt = E - blk * EPB;
    if (cnt > EPB) cnt = EPB;
    for (int k = t; k < cnt; k += 1024) {
        int row = rows_r[base + k];
        int b = row >> BSHIFT;
        int pos = atomicAdd(&cursor[b], 1);
        uint32_t key = ((uint32_t)(row & (NRB - 1)) << KEYSHIFT) | (uint32_t)cols_r[base + k];
        rec_r[pos] = make_uint2(key, __float_as_uint(vals_r[base + k]));
    }
}

// ---------------------------------------------------------------------------
// Build pass C: per-bucket counting sort by rel-row, FULLY IN LDS.
// One 256-thread block per 256-row bucket (~2560 edges = 20KB). Sort into
// the LDS staging buffer, then write srec as one dense coalesced stream —
// the scattered 8B srec writes of the old version are gone. Emits row_ptr.
// Legacy global-scatter fallback if a bucket exceeds CCAP (p ~ 0).
// ---------------------------------------------------------------------------
__global__ __launch_bounds__(256) void bucket_sort_kernel(
    const uint2* __restrict__ rec, uint2* __restrict__ srec,
    const int* __restrict__ bptr, int* __restrict__ rp, int K, int N,
    long long rStride, long long pStride, long long rpStride) {
    __shared__ uint2 staged[CCAP];  // 24KB
    __shared__ int hist[NRB];
    __shared__ int excl[NRB];
    int r = blockIdx.y;
    const uint2* rec_r = rec + (size_t)r * rStride;
    uint2* srec_r = srec + (size_t)r * rStride;
    const int* bptr_r = bptr + (size_t)r * pStride;
    int* rp_r = rp + (size_t)r * rpStride;
    int b = blockIdx.x;
    int t = threadIdx.x;          // 256 threads == NRB
    hist[t] = 0;
    __syncthreads();
    int start = bptr_r[b], end = bptr_r[b + 1];
    int m = end - start;
    for (int e = start + t; e < end; e += 256)
        atomicAdd(&hist[rec_r[e].x >> KEYSHIFT], 1);
    __syncthreads();
    int v = hist[t];
    excl[t] = v;
    __syncthreads();
    for (int off = 1; off < 256; off <<= 1) {
        int x = (t >= off) ? excl[t - off] : 0;
        __syncthreads();
        excl[t] += x;
        __syncthreads();
    }
    int ex = excl[t] - v;
    excl[t] = ex;                 // own-slot overwrite, no cross-read yet
    hist[t] = 0;                  // reuse as cursors
    int row = b * NRB + t;
    if (row < N) rp_r[row] = start + ex;
    if (b == K - 1 && t == 0) rp_r[N] = bptr_r[K];
    __syncthreads();
    if (m <= CCAP) {
        for (int e = start + t; e < end; e += 256) {
            uint2 rr = rec_r[e];
            int rel = (int)(rr.x >> KEYSHIFT);
            int pos = excl[rel] + atomicAdd(&hist[rel], 1);
            staged[pos] = rr;
        }
        __syncthreads();
        for (int i = t; i < m; i += 256)
            srec_r[start + i] = staged[i];
    } else {
        for (int e = start + t; e < end; e += 256) {
            uint2 rr = rec_r[e];
            int rel = (int)(rr.x >> KEYSHIFT);
            int pos = start + excl[rel] + atomicAdd(&hist[rel], 1);
            srec_r[pos] = rr;
        }
    }
}

// ---------------------------------------------------------------------------
// Per-rating MLP: h = leaky_relu(x @ W1a + c1) @ W2 + b2
// LDS: one W tile + one X/T tile (reused) = 33 KB; 16B-group XOR swizzle
// keeps all LDS streams conflict-free. prev = h; out_acc (flagged rows):
// init ? store : RMW-add (init at r=0 replaces the 25.6MB memset).
// ---------------------------------------------------------------------------
__global__ __launch_bounds__(256) void mlp_kernel(
    const float* __restrict__ user_emb, const float* __restrict__ item_emb,
    const float* __restrict__ W1, const float* __restrict__ W2,
    const float* __restrict__ c1_all, const float* __restrict__ b2,
    float* __restrict__ prev, float* __restrict__ out_acc,
    const unsigned char* __restrict__ flag, int r, int n_rows, int U, int init) {
    __shared__ float sW[64 * 64];   // [k][j], linear
    __shared__ float sX[64 * 64];   // [k][i], group-swizzled; reused for T
    __shared__ float sc1[64];
    __shared__ float sb2v[64];

    int t = threadIdx.x;
    int row0 = blockIdx.x * 64;
    const float* W1r = W1 + (size_t)r * (128 * 64);
    const float* W2r = W2 + (size_t)r * (64 * 64);

    #pragma unroll
    for (int q = 0; q < 4; q++) {
        int f = t + 256 * q;
        int k = f >> 4, c = (f & 15) * 4;
        *(float4*)(sW + k * 64 + c) = *(const float4*)(W1r + k * 64 + c);
    }
    #pragma unroll
    for (int q = 0; q < 4; q++) {
        int f = t + 256 * q;
        int i = f & 63;
        int c = (f >> 6) * 4;
        int nrow = row0 + i;
        float4 xv = make_float4(0.f, 0.f, 0.f, 0.f);
        if (nrow < n_rows) {
            const float* src = (nrow < U) ? (user_emb + (size_t)nrow * 64)
                                          : (item_emb + (size_t)(nrow - U) * 64);
            xv = *(const float4*)(src + c);
        }
        int gi = i >> 2, w = i & 3;
        sX[(c + 0) * 64 + 4 * (gi ^ ((c + 0) & 15)) + w] = xv.x;
        sX[(c + 1) * 64 + 4 * (gi ^ ((c + 1) & 15)) + w] = xv.y;
        sX[(c + 2) * 64 + 4 * (gi ^ ((c + 2) & 15)) + w] = xv.z;
        sX[(c + 3) * 64 + 4 * (gi ^ ((c + 3) & 15)) + w] = xv.w;
    }
    if (t < 64) sc1[t] = c1_all[r * 64 + t];
    else if (t < 128) sb2v[t - 64] = b2[r * 64 + (t - 64)];
    __syncthreads();

    int gi = t & 15;
    int i0 = gi * 4, j0 = (t >> 4) * 4;
    float acc[4][4];
    #pragma unroll
    for (int a = 0; a < 4; a++)
        #pragma unroll
        for (int b = 0; b < 4; b++) acc[a][b] = sc1[j0 + b];
    for (int k = 0; k < 64; k++) {
        float4 xv = *(const float4*)(sX + k * 64 + 4 * (gi ^ (k & 15)));
        float4 wv = *(const float4*)(sW + k * 64 + j0);
        float xs[4] = {xv.x, xv.y, xv.z, xv.w};
        float ws[4] = {wv.x, wv.y, wv.z, wv.w};
        #pragma unroll
        for (int a = 0; a < 4; a++)
            #pragma unroll
            for (int b = 0; b < 4; b++) acc[a][b] += xs[a] * ws[b];
    }
    __syncthreads();

    #pragma unroll
    for (int b = 0; b < 4; b++) {
        int k = j0 + b;
        float4 tv;
        tv.x = (acc[0][b] >= 0.f) ? acc[0][b] : 0.01f * acc[0][b];
        tv.y = (acc[1][b] >= 0.f) ? acc[1][b] : 0.01f * acc[1][b];
        tv.z = (acc[2][b] >= 0.f) ? acc[2][b] : 0.01f * acc[2][b];
        tv.w = (acc[3][b] >= 0.f) ? acc[3][b] : 0.01f * acc[3][b];
        *(float4*)(sX + k * 64 + 4 * (gi ^ (k & 15))) = tv;
    }
    #pragma unroll
    for (int q = 0; q < 4; q++) {
        int f = t + 256 * q;
        int k = f >> 4, c = (f & 15) * 4;
        *(float4*)(sW + k * 64 + c) = *(const float4*)(W2r + k * 64 + c);
    }
    __syncthreads();

    #pragma unroll
    for (int a = 0; a < 4; a++)
        #pragma unroll
        for (int b = 0; b < 4; b++) acc[a][b] = sb2v[j0 + b];
    for (int k = 0; k < 64; k++) {
        float4 xv = *(const float4*)(sX + k * 64 + 4 * (gi ^ (k & 15)));
        float4 wv = *(const float4*)(sW + k * 64 + j0);
        float xs[4] = {xv.x, xv.y, xv.z, xv.w};
        float ws[4] = {wv.x, wv.y, wv.z, wv.w};
        #pragma unroll
        for (int a = 0; a < 4; a++)
            #pragma unroll
            for (int b = 0; b < 4; b++) acc[a][b] += xs[a] * ws[b];
    }
    #pragma unroll
    for (int a = 0; a < 4; a++) {
        int nrow = row0 + i0 + a;
        if (nrow < n_rows) {
            float4 hv = make_float4(acc[a][0], acc[a][1], acc[a][2], acc[a][3]);
            *(float4*)(prev + (size_t)nrow * 64 + j0) = hv;
            if (flag[nrow]) {
                float* o = out_acc + (size_t)nrow * 64 + j0;
                if (init) {
                    *(float4*)o = hv;
                } else {
                    float4 ov = *(const float4*)o;
                    ov.x += hv.x; ov.y += hv.y; ov.z += hv.z; ov.w += hv.w;
                    *(float4*)o = ov;
                }
            }
        }
    }
}

// ---------------------------------------------------------------------------
// Gather-SpMM (layers 0/1): wave = 1 row; 4 edge-groups x 16 lanes x float4
// (full 256B row consumed per gather). 8 edges in flight per wave.
// R10/R12 proven form: plain uint2 loads, plain float4 store.
// ---------------------------------------------------------------------------
__global__ __launch_bounds__(256) void spmm_kernel(
    const float* __restrict__ prev, float* __restrict__ next,
    float* __restrict__ out_acc, const int* __restrict__ rp,
    const uint2* __restrict__ rec, const unsigned char* __restrict__ flag, int n) {
    int wave = (int)((blockIdx.x * (unsigned)blockDim.x + threadIdx.x) >> 6);
    int lane = threadIdx.x & 63;
    if (wave >= n) return;
    int sub = lane >> 4;      // edge group 0..3
    int dl = lane & 15;       // dims [dl*4, dl*4+4)
    int s = rp[wave], e2 = rp[wave + 1];
    float ax = 0.f, ay = 0.f, az = 0.f, aw = 0.f;
    int e = s + sub;
    for (; e + 4 < e2; e += 8) {
        uint2 r0 = rec[e];
        uint2 r1 = rec[e + 4];
        float4 p0 = *(const float4*)(prev + (size_t)(r0.x & COLMASK) * 64 + dl * 4);
        float4 p1 = *(const float4*)(prev + (size_t)(r1.x & COLMASK) * 64 + dl * 4);
        float v0 = __uint_as_float(r0.y), v1 = __uint_as_float(r1.y);
        ax += v0 * p0.x; ay += v0 * p0.y; az += v0 * p0.z; aw += v0 * p0.w;
        ax += v1 * p1.x; ay += v1 * p1.y; az += v1 * p1.z; aw += v1 * p1.w;
    }
    if (e < e2) {
        uint2 r0 = rec[e];
        float4 p0 = *(const float4*)(prev + (size_t)(r0.x & COLMASK) * 64 + dl * 4);
        float v0 = __uint_as_float(r0.y);
        ax += v0 * p0.x; ay += v0 * p0.y; az += v0 * p0.z; aw += v0 * p0.w;
    }
    ax += __shfl_xor(ax, 16); ay += __shfl_xor(ay, 16);
    az += __shfl_xor(az, 16); aw += __shfl_xor(aw, 16);
    ax += __shfl_xor(ax, 32); ay += __shfl_xor(ay, 32);
    az += __shfl_xor(az, 32); aw += __shfl_xor(aw, 32);
    if (sub == 0) {
        *(float4*)(next + (size_t)wave * 64 + dl * 4) = make_float4(ax, ay, az, aw);
    } else if (sub == 1 && flag[wave]) {
        float* o = out_acc + (size_t)wave * 64 + dl * 4;
        float4 ov = *(const float4*)o;
        ov.x += ax; ov.y += ay; ov.z += az; ov.w += aw;
        *(float4*)o = ov;
    }
}

// ---------------------------------------------------------------------------
// Layer-2 (masked) SpMM: only rows in flist. Same float4-lane layout.
// ---------------------------------------------------------------------------
__global__ __launch_bounds__(256) void spmm_masked_kernel(
    const float* __restrict__ prev, float* __restrict__ out_acc,
    const int* __restrict__ rp, const uint2* __restrict__ rec,
    unsigned long long maskbits, const int* __restrict__ flist,
    const int* __restrict__ fcount) {
    int w = (int)((blockIdx.x * (unsigned)blockDim.x + threadIdx.x) >> 6);
    int lane = threadIdx.x & 63;
    if (w >= *fcount) return;
    int sub = lane >> 4;
    int dl = lane & 15;
    int row = flist[w];
    int s = rp[row], e2 = rp[row + 1];
    float ax = 0.f, ay = 0.f, az = 0.f, aw = 0.f;
    int e = s + sub;
    for (; e + 4 < e2; e += 8) {
        uint2 r0 = rec[e];
        uint2 r1 = rec[e + 4];
        float4 p0 = *(const float4*)(prev + (size_t)(r0.x & COLMASK) * 64 + dl * 4);
        float4 p1 = *(const float4*)(prev + (size_t)(r1.x & COLMASK) * 64 + dl * 4);
        float v0 = __uint_as_float(r0.y), v1 = __uint_as_float(r1.y);
        ax += v0 * p0.x; ay += v0 * p0.y; az += v0 * p0.z; aw += v0 * p0.w;
        ax += v1 * p1.x; ay += v1 * p1.y; az += v1 * p1.z; aw += v1 * p1.w;
    }
    if (e < e2) {
        uint2 r0 = rec[e];
        float4 p0 = *(const float4*)(prev + (size_t)(r0.x & COLMASK) * 64 + dl * 4);
        float v0 = __uint_as_float(r0.y);
        ax += v0 * p0.x; ay += v0 * p0.y; az += v0 * p0.z; aw += v0 * p0.w;
    }
    ax += __shfl_xor(ax, 16); ay += __shfl_xor(ay, 16);
    az += __shfl_xor(az, 16); aw += __shfl_xor(aw, 16);
    ax += __shfl_xor(ax, 32); ay += __shfl_xor(ay, 32);
    az += __shfl_xor(az, 32); aw += __shfl_xor(aw, 32);
    if (sub == 0) {
        const float* pv = prev + (size_t)row * 64 + dl * 4;
        float4 pvv = *(const float4*)pv;
        float rx = ((maskbits >> (dl * 4 + 0)) & 1ull) ? ax : pvv.x;
        float ry = ((maskbits >> (dl * 4 + 1)) & 1ull) ? ay : pvv.y;
        float rz = ((maskbits >> (dl * 4 + 2)) & 1ull) ? az : pvv.z;
        float rw = ((maskbits >> (dl * 4 + 3)) & 1ull) ? aw : pvv.w;
        float* o = out_acc + (size_t)row * 64 + dl * 4;
        float4 ov = *(const float4*)o;
        ov.x += rx; ov.y += ry; ov.z += rz; ov.w += rw;
        *(float4*)o = ov;
    }
}

// ---------------------------------------------------------------------------
// Final: out[b] = (1/R^2) * dot(out_acc[users[b]], out_acc[U+items[b]])
// ---------------------------------------------------------------------------
__global__ __launch_bounds__(256) void dot_kernel(
    const float* __restrict__ out_acc, const int* __restrict__ users,
    const int* __restrict__ items, float* __restrict__ out,
    int Bn, int U, float scale) {
    int w = (int)((blockIdx.x * (unsigned)blockDim.x + threadIdx.x) >> 6);
    int lane = threadIdx.x & 63;
    if (w >= Bn) return;
    int u = users[w], it = items[w];
    float a = out_acc[(size_t)u * 64 + lane];
    float c = out_acc[((size_t)(U + it)) * 64 + lane];
    float p = a * c;
    #pragma unroll
    for (int off = 32; off > 0; off >>= 1) p += __shfl_down(p, off);
    if (lane == 0) out[w] = p * scale;
}

// ---------------------------------------------------------------------------
extern "C" void kernel_launch(void* const* d_in, const int* in_sizes, int n_in,
                              void* d_out, int out_size, void* d_ws, size_t ws_size,
                              hipStream_t stream) {
    const int* users = (const int*)d_in[0];
    const int* items = (const int*)d_in[1];
    const float* user_emb = (const float*)d_in[2];
    const float* item_emb = (const float*)d_in[3];
    const float* rating_emb = (const float*)d_in[4];
    const float* W1 = (const float*)d_in[5];
    const float* b1 = (const float*)d_in[6];
    const float* W2 = (const float*)d_in[7];
    const float* b2 = (const float*)d_in[8];
    const int* rows = (const int*)d_in[9];
    const int* cols = (const int*)d_in[10];
    const float* vals = (const float*)d_in[11];
    float* out = (float*)d_out;

    const int Dd = 64;
    int U = in_sizes[2] / Dd;
    int I = in_sizes[3] / Dd;
    int R = in_sizes[4] / Dd;
    int N = U + I;
    int E = in_sizes[9] / R;
    int Bn = in_sizes[0];
    int K = (N + NRB - 1) / NRB;    // 256-row buckets; K+1 <= 2048
    int nb = (E + EPB - 1) / EPB;   // count/scatter blocks per rating

    auto al = [](size_t b) { return (b + 255) & ~(size_t)255; };
    size_t base_need = 3 * al((size_t)N * 64 * 4) + al((size_t)R * K * 4)
        + al((size_t)R * (K + 1) * 4) + al((size_t)R * nb * K * 4)
        + al((size_t)R * (N + 1) * 4) + al((size_t)R * 64 * 4)
        + al((size_t)N) + al((size_t)2 * Bn * 4) + al(4);
    size_t rec_one = al((size_t)E * 8);
    size_t rec_all = al((size_t)E * 8 * R);
    // Batched build needs rec+srec for all R ratings simultaneously.
    int batched = (ws_size >= base_need + 2 * rec_all + 65536) ? 1 : 0;
    size_t recsz = batched ? rec_all : rec_one;

    char* p = (char*)d_ws;
    auto carve = [&](size_t bytes) -> char* {
        char* q = p;
        p += (bytes + 255) & ~(size_t)255;
        return q;
    };
    float* out_acc = (float*)carve((size_t)N * 64 * 4);
    float* bufA = (float*)carve((size_t)N * 64 * 4);
    float* bufB = (float*)carve((size_t)N * 64 * 4);
    uint2* rec = (uint2*)carve(recsz);
    uint2* srec = (uint2*)carve(recsz);
    int* gcnt = (int*)carve((size_t)R * K * 4);
    int* bptr = (int*)carve((size_t)R * (K + 1) * 4);
    int* blockBase = (int*)carve((size_t)R * nb * K * 4);
    int* row_ptr = (int*)carve((size_t)R * (N + 1) * 4);
    float* c1_all = (float*)carve((size_t)R * 64 * 4);
    unsigned char* flag = (unsigned char*)carve((size_t)N);
    int* flist = (int*)carve((size_t)2 * Bn * 4);
    int* fcount = (int*)carve(4);

    uint64_t maskbits = compute_mask_bits();

    hipMemsetAsync(flag, 0, (size_t)N, stream);
    hipMemsetAsync(fcount, 0, 4, stream);
    hipMemsetAsync(gcnt, 0, (size_t)R * K * 4, stream);

    flag_kernel<<<(2 * Bn + 255) / 256, 256, 0, stream>>>(users, items, flag, Bn, U);
    flist_kernel<<<(N + 255) / 256, 256, 0, stream>>>(flag, flist, fcount, N);
    c1_kernel<<<R, 64, 0, stream>>>(rating_emb, W1, b1, c1_all);

    // Build pass A (batched over ratings) + per-rating scans
    dim3 cgrid(nb, R);
    bucket_count_kernel<<<cgrid, 1024, 0, stream>>>(rows, gcnt, blockBase, E, K, nb);
    bucket_scan_kernel<<<R, 256, 0, stream>>>(gcnt, bptr, K);

    if (batched) {
        dim3 sgrid(nb, R);
        if (K <= 512)
            bucket_scatter_kernel<<<sgrid, 1024, 0, stream>>>(
                rows, cols, vals, bptr, blockBase, rec, E, K,
                (long long)E, (long long)(K + 1), (long long)nb * K, (long long)E);
        else
            bucket_scatter_legacy<<<sgrid, 1024, 0, stream>>>(
                rows, cols, vals, bptr, blockBase, rec, E, K,
                (long long)E, (long long)(K + 1), (long long)nb * K, (long long)E);
        dim3 ogrid(K, R);
        bucket_sort_kernel<<<ogrid, 256, 0, stream>>>(
            rec, srec, bptr, row_ptr, K, N,
            (long long)E, (long long)(K + 1), (long long)(N + 1));
    }

    int spmm_blocks = (N + 3) / 4;
    int masked_blocks = (2 * Bn + 3) / 4;
    for (int r = 0; r < R; r++) {
        const int* bptr_r = bptr + (size_t)r * (K + 1);
        int* rp_r = row_ptr + (size_t)r * (N + 1);
        uint2* srec_r = batched ? (srec + (size_t)r * E) : srec;

        if (!batched) {
            dim3 sgrid(nb, 1);
            if (K <= 512)
                bucket_scatter_kernel<<<sgrid, 1024, 0, stream>>>(
                    rows + (size_t)r * E, cols + (size_t)r * E, vals + (size_t)r * E,
                    bptr_r, blockBase + (size_t)r * nb * K, rec, E, K, 0, 0, 0, 0);
            else
                bucket_scatter_legacy<<<sgrid, 1024, 0, stream>>>(
                    rows + (size_t)r * E, cols + (size_t)r * E, vals + (size_t)r * E,
                    bptr_r, blockBase + (size_t)r * nb * K, rec, E, K, 0, 0, 0, 0);
            dim3 ogrid(K, 1);
            bucket_sort_kernel<<<ogrid, 256, 0, stream>>>(
                rec, srec, bptr_r, rp_r, K, N, 0, 0, 0);
        }

        mlp_kernel<<<(N + 63) / 64, 256, 0, stream>>>(user_emb, item_emb, W1, W2,
                                                      c1_all, b2, bufA, out_acc,
                                                      flag, r, N, U, (r == 0) ? 1 : 0);

        spmm_kernel<<<spmm_blocks, 256, 0, stream>>>(bufA, bufB, out_acc, rp_r,
                                                     srec_r, flag, N);
        spmm_kernel<<<spmm_blocks, 256, 0, stream>>>(bufB, bufA, out_acc, rp_r,
                                                     srec_r, flag, N);
        spmm_masked_kernel<<<masked_blocks, 256, 0, stream>>>(bufA, out_acc, rp_r,
                                                              srec_r, maskbits,
                                                              flist, fcount);
    }

    float scale = 1.0f / (float)(R * R);
    dot_kernel<<<(Bn * 64 + 255) / 256, 256, 0, stream>>>(out_acc, users, items, out,
                                                          Bn, U, scale);
}

// Round 3
// 848.663 us; speedup vs baseline: 1.1803x; 1.0670x over previous
//
#include <hip/hip_runtime.h>
#include <hip/hip_bf16.h>
#include <cstdint>
#include <cstddef>

#define KEYSHIFT 20
#define COLMASK 0xFFFFFu
#define EPB 8192    // edges per count/scatter block (1024 threads x 8)
#define SUB 4096    // staged sub-chunk inside scatter (fits 54KB LDS)
#define BSHIFT 8    // 256 rows per bucket
#define NRB 256     // rows per bucket (1 << BSHIFT)
#define CCAP 3072   // LDS sort capacity per bucket (avg ~2560, max ~2750)

// bf16 pack/unpack: gathered operand is bf16 (halves the L2-miss fill
// traffic the spmm is pinned on); all accumulation stays fp32.
// R2 resubmit: prior run died on container infra, not kernel evidence.
__device__ __forceinline__ unsigned short f2bf(float f) {
    uint32_t u = __float_as_uint(f);
    u += ((u >> 16) & 1u) + 0x7fffu;   // RNE
    return (unsigned short)(u >> 16);
}
__device__ __forceinline__ float bf2f(unsigned short h) {
    return __uint_as_float(((uint32_t)h) << 16);
}

// ---------------------------------------------------------------------------
// Host-side reproduction of np.random.RandomState(2).permutation(64):
// MT19937 init_genrand(2), Fisher-Yates with numpy random_interval
// (mask+rejection). Mask bit d = (perm[d] >= 38).
// ---------------------------------------------------------------------------
static uint64_t compute_mask_bits() {
    uint32_t mt[624];
    mt[0] = 2u;
    for (int i = 1; i < 624; i++)
        mt[i] = 1812433253u * (mt[i - 1] ^ (mt[i - 1] >> 30)) + (uint32_t)i;
    int mti = 624;
    auto genrand = [&]() -> uint32_t {
        if (mti >= 624) {
            for (int k = 0; k < 624; k++) {
                uint32_t y = (mt[k] & 0x80000000u) | (mt[(k + 1) % 624] & 0x7fffffffu);
                mt[k] = mt[(k + 397) % 624] ^ (y >> 1) ^ ((y & 1u) ? 2567483615u : 0u);
            }
            mti = 0;
        }
        uint32_t y = mt[mti++];
        y ^= y >> 11;
        y ^= (y << 7) & 2636928640u;
        y ^= (y << 15) & 4022730752u;
        y ^= y >> 18;
        return y;
    };
    int arr[64];
    for (int i = 0; i < 64; i++) arr[i] = i;
    for (int i = 63; i >= 1; i--) {
        uint32_t mask = (uint32_t)i;
        mask |= mask >> 1; mask |= mask >> 2; mask |= mask >> 4;
        mask |= mask >> 8; mask |= mask >> 16;
        uint32_t v;
        do { v = genrand() & mask; } while (v > (uint32_t)i);
        int tmp = arr[i]; arr[i] = arr[v]; arr[v] = tmp;
    }
    uint64_t bits = 0;
    for (int d = 0; d < 64; d++)
        if (arr[d] >= 38) bits |= (1ull << d);
    return bits;
}

// ---------------------------------------------------------------------------
// Output-row flag set + compacted list (rows read by the final dot).
// ---------------------------------------------------------------------------
__global__ void flag_kernel(const int* __restrict__ users, const int* __restrict__ items,
                            unsigned char* __restrict__ flag, int B, int U) {
    int i = blockIdx.x * 256 + threadIdx.x;
    if (i < B) flag[users[i]] = 1;
    else if (i < 2 * B) flag[U + items[i - B]] = 1;
}

__global__ void flist_kernel(const unsigned char* __restrict__ flag,
                             int* __restrict__ flist, int* __restrict__ fcount, int n) {
    int i = blockIdx.x * 256 + threadIdx.x;
    if (i < n && flag[i]) {
        int p = atomicAdd(fcount, 1);
        flist[p] = i;
    }
}

// ---------------------------------------------------------------------------
// Per-rating constant c1[r][j] = b1[r][j] + sum_k e_r[k] * W1[r][64+k][j].
// ---------------------------------------------------------------------------
__global__ void c1_kernel(const float* __restrict__ rating_emb, const float* __restrict__ W1,
                          const float* __restrict__ b1, float* __restrict__ c1_all) {
    int r = blockIdx.x;
    int t = threadIdx.x;  // 64 threads
    const float* W1r = W1 + (size_t)r * (128 * 64);
    float acc = b1[r * 64 + t];
    for (int k = 0; k < 64; k++)
        acc += rating_emb[r * 64 + k] * W1r[(64 + k) * 64 + t];
    c1_all[r * 64 + t] = acc;
}

// ---------------------------------------------------------------------------
// Build pass A (batched over ratings): LDS histogram over K=ceil(N/256) row
// buckets, then ONE global atomicAdd per (block,bucket) to reserve a range.
// ---------------------------------------------------------------------------
__global__ __launch_bounds__(1024) void bucket_count_kernel(
    const int* __restrict__ rows, int* __restrict__ gcnt,
    int* __restrict__ blockBase, int E, int K, int nb) {
    __shared__ int hist[2048];
    int r = blockIdx.y, blk = blockIdx.x, t = threadIdx.x;
    for (int i = t; i < K; i += 1024) hist[i] = 0;
    __syncthreads();
    size_t base = (size_t)r * E + (size_t)blk * EPB;
    int cnt = E - blk * EPB;
    if (cnt > EPB) cnt = EPB;
    for (int k = t; k < cnt; k += 1024)
        atomicAdd(&hist[rows[base + k] >> BSHIFT], 1);
    __syncthreads();
    for (int i = t; i < K; i += 1024) {
        int c = hist[i];
        int bb = (c > 0) ? atomicAdd(&gcnt[r * K + i], c) : 0;
        blockBase[((size_t)r * nb + blk) * K + i] = bb;
    }
}

// ---------------------------------------------------------------------------
// Exclusive scan of K bucket counts -> bptr[K+1] per rating (grid.x = R).
// ---------------------------------------------------------------------------
__global__ void bucket_scan_kernel(const int* __restrict__ gcnt,
                                   int* __restrict__ bptr, int K) {
    __shared__ int sh[256];
    int r = blockIdx.x;
    int t = threadIdx.x;
    int base = t * 8;
    int v[8];
    int s = 0;
    #pragma unroll
    for (int j = 0; j < 8; j++) {
        int idx = base + j;
        v[j] = (idx < K) ? gcnt[r * K + idx] : 0;
        s += v[j];
    }
    sh[t] = s;
    __syncthreads();
    for (int off = 1; off < 256; off <<= 1) {
        int x = (t >= off) ? sh[t - off] : 0;
        __syncthreads();
        sh[t] += x;
        __syncthreads();
    }
    int run = sh[t] - s;
    #pragma unroll
    for (int j = 0; j < 8; j++) {
        int idx = base + j;
        if (idx <= K) bptr[r * (K + 1) + idx] = run;
        run += v[j];
    }
}

// ---------------------------------------------------------------------------
// Build pass B: LDS-STAGED scatter into bucket-grouped rec (K <= 512).
// Each 4096-edge sub-chunk is histogrammed, scanned, staged bucket-grouped
// in LDS with its final global address, then written out linearly.
// ---------------------------------------------------------------------------
__global__ __launch_bounds__(1024) void bucket_scatter_kernel(
    const int* __restrict__ rows, const int* __restrict__ cols,
    const float* __restrict__ vals, const int* __restrict__ bptr,
    const int* __restrict__ blockBase, uint2* __restrict__ rec,
    int E, int K, long long eStride, long long pStride,
    long long bbStride, long long rStride) {
    __shared__ uint2 staged[SUB];   // 32KB
    __shared__ int gaddr[SUB];      // 16KB final rec index per staged slot
    __shared__ int cursor[512];     // running global cursor per bucket
    __shared__ int lhist[512];      // per-subchunk count -> local base
    __shared__ int aux[512];        // scan scratch -> goff (=gbase-localbase)
    int r = blockIdx.y;
    const int* rows_r = rows + (size_t)r * eStride;
    const int* cols_r = cols + (size_t)r * eStride;
    const float* vals_r = vals + (size_t)r * eStride;
    const int* bptr_r = bptr + (size_t)r * pStride;
    const int* bb_r = blockBase + (size_t)r * bbStride;
    uint2* rec_r = rec + (size_t)r * rStride;
    int blk = blockIdx.x, t = threadIdx.x;
    if (t < 512)
        cursor[t] = (t < K) ? (bptr_r[t] + bb_r[(size_t)blk * K + t]) : 0;
    size_t base = (size_t)blk * EPB;
    int cnt = E - blk * EPB;
    if (cnt > EPB) cnt = EPB;
    for (int c0 = 0; c0 < cnt; c0 += SUB) {
        int scnt = cnt - c0;
        if (scnt > SUB) scnt = SUB;
        if (t < 512) lhist[t] = 0;
        __syncthreads();
        int bkt_[4], lpos_[4];
        uint2 rv_[4];
        #pragma unroll
        for (int q = 0; q < 4; q++) {
            int kk = (q << 10) + t;
            bkt_[q] = -1;
            if (kk < scnt) {
                size_t g = base + c0 + kk;
                int row = rows_r[g];
                int b = row >> BSHIFT;
                bkt_[q] = b;
                rv_[q] = make_uint2(((uint32_t)(row & (NRB - 1)) << KEYSHIFT) |
                                        (uint32_t)cols_r[g],
                                    __float_as_uint(vals_r[g]));
                lpos_[q] = atomicAdd(&lhist[b], 1);
            }
        }
        __syncthreads();
        int v = (t < 512) ? lhist[t] : 0;
        if (t < 512) aux[t] = v;
        __syncthreads();
        for (int off = 1; off < 512; off <<= 1) {
            int x = 0;
            if (t >= off && t < 512) x = aux[t - off];
            __syncthreads();
            if (t < 512) aux[t] += x;
            __syncthreads();
        }
        if (t < 512) {
            int ex = aux[t] - v;     // exclusive local base
            int gb = cursor[t];      // global base for this sub-chunk
            cursor[t] = gb + v;
            lhist[t] = ex;
            aux[t] = gb - ex;        // goff: gaddr = goff[b] + staged_idx
        }
        __syncthreads();
        #pragma unroll
        for (int q = 0; q < 4; q++) {
            if (bkt_[q] >= 0) {
                int sidx = lhist[bkt_[q]] + lpos_[q];
                staged[sidx] = rv_[q];
                gaddr[sidx] = aux[bkt_[q]] + sidx;
            }
        }
        __syncthreads();
        for (int i = t; i < scnt; i += 1024)
            rec_r[gaddr[i]] = staged[i];
        __syncthreads();
    }
}

// ---------------------------------------------------------------------------
// Build pass B legacy (direct scatter) — only used if K > 512.
// ---------------------------------------------------------------------------
__global__ __launch_bounds__(1024) void bucket_scatter_legacy(
    const int* __restrict__ rows, const int* __restrict__ cols,
    const float* __restrict__ vals, const int* __restrict__ bptr,
    const int* __restrict__ blockBase, uint2* __restrict__ rec,
    int E, int K, long long eStride, long long pStride,
    long long bbStride, long long rStride) {
    __shared__ int cursor[2048];
    int r = blockIdx.y;
    const int* rows_r = rows + (size_t)r * eStride;
    const int* cols_r = cols + (size_t)r * eStride;
    const float* vals_r = vals + (size_t)r * eStride;
    const int* bptr_r = bptr + (size_t)r * pStride;
    const int* bb_r = blockBase + (size_t)r * bbStride;
    uint2* rec_r = rec + (size_t)r * rStride;
    int blk = blockIdx.x, t = threadIdx.x;
    for (int i = t; i < K; i += 1024)
        cursor[i] = bptr_r[i] + bb_r[(size_t)blk * K + i];
    __syncthreads();
    size_t base = (size_t)blk * EPB;
    int cnt = E - blk * EPB;
    if (cnt > EPB) cnt = EPB;
    for (int k = t; k < cnt; k += 1024) {
        int row = rows_r[base + k];
        int b = row >> BSHIFT;
        int pos = atomicAdd(&cursor[b], 1);
        uint32_t key = ((uint32_t)(row & (NRB - 1)) << KEYSHIFT) | (uint32_t)cols_r[base + k];
        rec_r[pos] = make_uint2(key, __float_as_uint(vals_r[base + k]));
    }
}

// ---------------------------------------------------------------------------
// Build pass C: per-bucket counting sort by rel-row, FULLY IN LDS; srec
// written as one dense coalesced stream. Emits row_ptr.
// ---------------------------------------------------------------------------
__global__ __launch_bounds__(256) void bucket_sort_kernel(
    const uint2* __restrict__ rec, uint2* __restrict__ srec,
    const int* __restrict__ bptr, int* __restrict__ rp, int K, int N,
    long long rStride, long long pStride, long long rpStride) {
    __shared__ uint2 staged[CCAP];  // 24KB
    __shared__ int hist[NRB];
    __shared__ int excl[NRB];
    int r = blockIdx.y;
    const uint2* rec_r = rec + (size_t)r * rStride;
    uint2* srec_r = srec + (size_t)r * rStride;
    const int* bptr_r = bptr + (size_t)r * pStride;
    int* rp_r = rp + (size_t)r * rpStride;
    int b = blockIdx.x;
    int t = threadIdx.x;          // 256 threads == NRB
    hist[t] = 0;
    __syncthreads();
    int start = bptr_r[b], end = bptr_r[b + 1];
    int m = end - start;
    for (int e = start + t; e < end; e += 256)
        atomicAdd(&hist[rec_r[e].x >> KEYSHIFT], 1);
    __syncthreads();
    int v = hist[t];
    excl[t] = v;
    __syncthreads();
    for (int off = 1; off < 256; off <<= 1) {
        int x = (t >= off) ? excl[t - off] : 0;
        __syncthreads();
        excl[t] += x;
        __syncthreads();
    }
    int ex = excl[t] - v;
    excl[t] = ex;                 // own-slot overwrite, no cross-read yet
    hist[t] = 0;                  // reuse as cursors
    int row = b * NRB + t;
    if (row < N) rp_r[row] = start + ex;
    if (b == K - 1 && t == 0) rp_r[N] = bptr_r[K];
    __syncthreads();
    if (m <= CCAP) {
        for (int e = start + t; e < end; e += 256) {
            uint2 rr = rec_r[e];
            int rel = (int)(rr.x >> KEYSHIFT);
            int pos = excl[rel] + atomicAdd(&hist[rel], 1);
            staged[pos] = rr;
        }
        __syncthreads();
        for (int i = t; i < m; i += 256)
            srec_r[start + i] = staged[i];
    } else {
        for (int e = start + t; e < end; e += 256) {
            uint2 rr = rec_r[e];
            int rel = (int)(rr.x >> KEYSHIFT);
            int pos = start + excl[rel] + atomicAdd(&hist[rel], 1);
            srec_r[pos] = rr;
        }
    }
}

// ---------------------------------------------------------------------------
// Per-rating MLP: h = leaky_relu(x @ W1a + c1) @ W2 + b2
// prev is written as bf16 (gather operand); out_acc stays fp32:
// init ? store : RMW-add (init at r=0 replaces the 25.6MB memset).
// ---------------------------------------------------------------------------
__global__ __launch_bounds__(256) void mlp_kernel(
    const float* __restrict__ user_emb, const float* __restrict__ item_emb,
    const float* __restrict__ W1, const float* __restrict__ W2,
    const float* __restrict__ c1_all, const float* __restrict__ b2,
    unsigned short* __restrict__ prev, float* __restrict__ out_acc,
    const unsigned char* __restrict__ flag, int r, int n_rows, int U, int init) {
    __shared__ float sW[64 * 64];   // [k][j], linear
    __shared__ float sX[64 * 64];   // [k][i], group-swizzled; reused for T
    __shared__ float sc1[64];
    __shared__ float sb2v[64];

    int t = threadIdx.x;
    int row0 = blockIdx.x * 64;
    const float* W1r = W1 + (size_t)r * (128 * 64);
    const float* W2r = W2 + (size_t)r * (64 * 64);

    #pragma unroll
    for (int q = 0; q < 4; q++) {
        int f = t + 256 * q;
        int k = f >> 4, c = (f & 15) * 4;
        *(float4*)(sW + k * 64 + c) = *(const float4*)(W1r + k * 64 + c);
    }
    #pragma unroll
    for (int q = 0; q < 4; q++) {
        int f = t + 256 * q;
        int i = f & 63;
        int c = (f >> 6) * 4;
        int nrow = row0 + i;
        float4 xv = make_float4(0.f, 0.f, 0.f, 0.f);
        if (nrow < n_rows) {
            const float* src = (nrow < U) ? (user_emb + (size_t)nrow * 64)
                                          : (item_emb + (size_t)(nrow - U) * 64);
            xv = *(const float4*)(src + c);
        }
        int gi = i >> 2, w = i & 3;
        sX[(c + 0) * 64 + 4 * (gi ^ ((c + 0) & 15)) + w] = xv.x;
        sX[(c + 1) * 64 + 4 * (gi ^ ((c + 1) & 15)) + w] = xv.y;
        sX[(c + 2) * 64 + 4 * (gi ^ ((c + 2) & 15)) + w] = xv.z;
        sX[(c + 3) * 64 + 4 * (gi ^ ((c + 3) & 15)) + w] = xv.w;
    }
    if (t < 64) sc1[t] = c1_all[r * 64 + t];
    else if (t < 128) sb2v[t - 64] = b2[r * 64 + (t - 64)];
    __syncthreads();

    int gi = t & 15;
    int i0 = gi * 4, j0 = (t >> 4) * 4;
    float acc[4][4];
    #pragma unroll
    for (int a = 0; a < 4; a++)
        #pragma unroll
        for (int b = 0; b < 4; b++) acc[a][b] = sc1[j0 + b];
    for (int k = 0; k < 64; k++) {
        float4 xv = *(const float4*)(sX + k * 64 + 4 * (gi ^ (k & 15)));
        float4 wv = *(const float4*)(sW + k * 64 + j0);
        float xs[4] = {xv.x, xv.y, xv.z, xv.w};
        float ws[4] = {wv.x, wv.y, wv.z, wv.w};
        #pragma unroll
        for (int a = 0; a < 4; a++)
            #pragma unroll
            for (int b = 0; b < 4; b++) acc[a][b] += xs[a] * ws[b];
    }
    __syncthreads();

    #pragma unroll
    for (int b = 0; b < 4; b++) {
        int k = j0 + b;
        float4 tv;
        tv.x = (acc[0][b] >= 0.f) ? acc[0][b] : 0.01f * acc[0][b];
        tv.y = (acc[1][b] >= 0.f) ? acc[1][b] : 0.01f * acc[1][b];
        tv.z = (acc[2][b] >= 0.f) ? acc[2][b] : 0.01f * acc[2][b];
        tv.w = (acc[3][b] >= 0.f) ? acc[3][b] : 0.01f * acc[3][b];
        *(float4*)(sX + k * 64 + 4 * (gi ^ (k & 15))) = tv;
    }
    #pragma unroll
    for (int q = 0; q < 4; q++) {
        int f = t + 256 * q;
        int k = f >> 4, c = (f & 15) * 4;
        *(float4*)(sW + k * 64 + c) = *(const float4*)(W2r + k * 64 + c);
    }
    __syncthreads();

    #pragma unroll
    for (int a = 0; a < 4; a++)
        #pragma unroll
        for (int b = 0; b < 4; b++) acc[a][b] = sb2v[j0 + b];
    for (int k = 0; k < 64; k++) {
        float4 xv = *(const float4*)(sX + k * 64 + 4 * (gi ^ (k & 15)));
        float4 wv = *(const float4*)(sW + k * 64 + j0);
        float xs[4] = {xv.x, xv.y, xv.z, xv.w};
        float ws[4] = {wv.x, wv.y, wv.z, wv.w};
        #pragma unroll
        for (int a = 0; a < 4; a++)
            #pragma unroll
            for (int b = 0; b < 4; b++) acc[a][b] += xs[a] * ws[b];
    }
    #pragma unroll
    for (int a = 0; a < 4; a++) {
        int nrow = row0 + i0 + a;
        if (nrow < n_rows) {
            float4 hv = make_float4(acc[a][0], acc[a][1], acc[a][2], acc[a][3]);
            ushort4 hb;
            hb.x = f2bf(hv.x); hb.y = f2bf(hv.y);
            hb.z = f2bf(hv.z); hb.w = f2bf(hv.w);
            *(ushort4*)(prev + (size_t)nrow * 64 + j0) = hb;
            if (flag[nrow]) {
                float* o = out_acc + (size_t)nrow * 64 + j0;
                if (init) {
                    *(float4*)o = hv;
                } else {
                    float4 ov = *(const float4*)o;
                    ov.x += hv.x; ov.y += hv.y; ov.z += hv.z; ov.w += hv.w;
                    *(float4*)o = ov;
                }
            }
        }
    }
}

// ---------------------------------------------------------------------------
// Gather-SpMM (layers 0/1): wave = 1 row; 4 edge-groups x 16 lanes.
// prev/next are bf16 (128B per gathered row); accumulation fp32.
// ---------------------------------------------------------------------------
__global__ __launch_bounds__(256) void spmm_kernel(
    const unsigned short* __restrict__ prev, unsigned short* __restrict__ next,
    float* __restrict__ out_acc, const int* __restrict__ rp,
    const uint2* __restrict__ rec, const unsigned char* __restrict__ flag, int n) {
    int wave = (int)((blockIdx.x * (unsigned)blockDim.x + threadIdx.x) >> 6);
    int lane = threadIdx.x & 63;
    if (wave >= n) return;
    int sub = lane >> 4;      // edge group 0..3
    int dl = lane & 15;       // dims [dl*4, dl*4+4)
    int s = rp[wave], e2 = rp[wave + 1];
    float ax = 0.f, ay = 0.f, az = 0.f, aw = 0.f;
    int e = s + sub;
    for (; e + 4 < e2; e += 8) {
        uint2 r0 = rec[e];
        uint2 r1 = rec[e + 4];
        ushort4 q0 = *(const ushort4*)(prev + (size_t)(r0.x & COLMASK) * 64 + dl * 4);
        ushort4 q1 = *(const ushort4*)(prev + (size_t)(r1.x & COLMASK) * 64 + dl * 4);
        float v0 = __uint_as_float(r0.y), v1 = __uint_as_float(r1.y);
        ax += v0 * bf2f(q0.x); ay += v0 * bf2f(q0.y);
        az += v0 * bf2f(q0.z); aw += v0 * bf2f(q0.w);
        ax += v1 * bf2f(q1.x); ay += v1 * bf2f(q1.y);
        az += v1 * bf2f(q1.z); aw += v1 * bf2f(q1.w);
    }
    if (e < e2) {
        uint2 r0 = rec[e];
        ushort4 q0 = *(const ushort4*)(prev + (size_t)(r0.x & COLMASK) * 64 + dl * 4);
        float v0 = __uint_as_float(r0.y);
        ax += v0 * bf2f(q0.x); ay += v0 * bf2f(q0.y);
        az += v0 * bf2f(q0.z); aw += v0 * bf2f(q0.w);
    }
    ax += __shfl_xor(ax, 16); ay += __shfl_xor(ay, 16);
    az += __shfl_xor(az, 16); aw += __shfl_xor(aw, 16);
    ax += __shfl_xor(ax, 32); ay += __shfl_xor(ay, 32);
    az += __shfl_xor(az, 32); aw += __shfl_xor(aw, 32);
    if (sub == 0) {
        ushort4 nv;
        nv.x = f2bf(ax); nv.y = f2bf(ay); nv.z = f2bf(az); nv.w = f2bf(aw);
        *(ushort4*)(next + (size_t)wave * 64 + dl * 4) = nv;
    } else if (sub == 1 && flag[wave]) {
        float* o = out_acc + (size_t)wave * 64 + dl * 4;
        float4 ov = *(const float4*)o;
        ov.x += ax; ov.y += ay; ov.z += az; ov.w += aw;
        *(float4*)o = ov;
    }
}

// ---------------------------------------------------------------------------
// Layer-2 (masked) SpMM: only rows in flist. bf16 prev, fp32 out_acc.
// ---------------------------------------------------------------------------
__global__ __launch_bounds__(256) void spmm_masked_kernel(
    const unsigned short* __restrict__ prev, float* __restrict__ out_acc,
    const int* __restrict__ rp, const uint2* __restrict__ rec,
    unsigned long long maskbits, const int* __restrict__ flist,
    const int* __restrict__ fcount) {
    int w = (int)((blockIdx.x * (unsigned)blockDim.x + threadIdx.x) >> 6);
    int lane = threadIdx.x & 63;
    if (w >= *fcount) return;
    int sub = lane >> 4;
    int dl = lane & 15;
    int row = flist[w];
    int s = rp[row], e2 = rp[row + 1];
    float ax = 0.f, ay = 0.f, az = 0.f, aw = 0.f;
    int e = s + sub;
    for (; e + 4 < e2; e += 8) {
        uint2 r0 = rec[e];
        uint2 r1 = rec[e + 4];
        ushort4 q0 = *(const ushort4*)(prev + (size_t)(r0.x & COLMASK) * 64 + dl * 4);
        ushort4 q1 = *(const ushort4*)(prev + (size_t)(r1.x & COLMASK) * 64 + dl * 4);
        float v0 = __uint_as_float(r0.y), v1 = __uint_as_float(r1.y);
        ax += v0 * bf2f(q0.x); ay += v0 * bf2f(q0.y);
        az += v0 * bf2f(q0.z); aw += v0 * bf2f(q0.w);
        ax += v1 * bf2f(q1.x); ay += v1 * bf2f(q1.y);
        az += v1 * bf2f(q1.z); aw += v1 * bf2f(q1.w);
    }
    if (e < e2) {
        uint2 r0 = rec[e];
        ushort4 q0 = *(const ushort4*)(prev + (size_t)(r0.x & COLMASK) * 64 + dl * 4);
        float v0 = __uint_as_float(r0.y);
        ax += v0 * bf2f(q0.x); ay += v0 * bf2f(q0.y);
        az += v0 * bf2f(q0.z); aw += v0 * bf2f(q0.w);
    }
    ax += __shfl_xor(ax, 16); ay += __shfl_xor(ay, 16);
    az += __shfl_xor(az, 16); aw += __shfl_xor(aw, 16);
    ax += __shfl_xor(ax, 32); ay += __shfl_xor(ay, 32);
    az += __shfl_xor(az, 32); aw += __shfl_xor(aw, 32);
    if (sub == 0) {
        ushort4 pq = *(const ushort4*)(prev + (size_t)row * 64 + dl * 4);
        float px = bf2f(pq.x), py = bf2f(pq.y), pz = bf2f(pq.z), pw = bf2f(pq.w);
        float rx = ((maskbits >> (dl * 4 + 0)) & 1ull) ? ax : px;
        float ry = ((maskbits >> (dl * 4 + 1)) & 1ull) ? ay : py;
        float rz = ((maskbits >> (dl * 4 + 2)) & 1ull) ? az : pz;
        float rw = ((maskbits >> (dl * 4 + 3)) & 1ull) ? aw : pw;
        float* o = out_acc + (size_t)row * 64 + dl * 4;
        float4 ov = *(const float4*)o;
        ov.x += rx; ov.y += ry; ov.z += rz; ov.w += rw;
        *(float4*)o = ov;
    }
}

// ---------------------------------------------------------------------------
// Final: out[b] = (1/R^2) * dot(out_acc[users[b]], out_acc[U+items[b]])
// ---------------------------------------------------------------------------
__global__ __launch_bounds__(256) void dot_kernel(
    const float* __restrict__ out_acc, const int* __restrict__ users,
    const int* __restrict__ items, float* __restrict__ out,
    int Bn, int U, float scale) {
    int w = (int)((blockIdx.x * (unsigned)blockDim.x + threadIdx.x) >> 6);
    int lane = threadIdx.x & 63;
    if (w >= Bn) return;
    int u = users[w], it = items[w];
    float a = out_acc[(size_t)u * 64 + lane];
    float c = out_acc[((size_t)(U + it)) * 64 + lane];
    float p = a * c;
    #pragma unroll
    for (int off = 32; off > 0; off >>= 1) p += __shfl_down(p, off);
    if (lane == 0) out[w] = p * scale;
}

// ---------------------------------------------------------------------------
extern "C" void kernel_launch(void* const* d_in, const int* in_sizes, int n_in,
                              void* d_out, int out_size, void* d_ws, size_t ws_size,
                              hipStream_t stream) {
    const int* users = (const int*)d_in[0];
    const int* items = (const int*)d_in[1];
    const float* user_emb = (const float*)d_in[2];
    const float* item_emb = (const float*)d_in[3];
    const float* rating_emb = (const float*)d_in[4];
    const float* W1 = (const float*)d_in[5];
    const float* b1 = (const float*)d_in[6];
    const float* W2 = (const float*)d_in[7];
    const float* b2 = (const float*)d_in[8];
    const int* rows = (const int*)d_in[9];
    const int* cols = (const int*)d_in[10];
    const float* vals = (const float*)d_in[11];
    float* out = (float*)d_out;

    const int Dd = 64;
    int U = in_sizes[2] / Dd;
    int I = in_sizes[3] / Dd;
    int R = in_sizes[4] / Dd;
    int N = U + I;
    int E = in_sizes[9] / R;
    int Bn = in_sizes[0];
    int K = (N + NRB - 1) / NRB;    // 256-row buckets; K+1 <= 2048
    int nb = (E + EPB - 1) / EPB;   // count/scatter blocks per rating

    auto al = [](size_t b) { return (b + 255) & ~(size_t)255; };
    size_t base_need = al((size_t)N * 64 * 4) + 2 * al((size_t)N * 64 * 2)
        + al((size_t)R * K * 4)
        + al((size_t)R * (K + 1) * 4) + al((size_t)R * nb * K * 4)
        + al((size_t)R * (N + 1) * 4) + al((size_t)R * 64 * 4)
        + al((size_t)N) + al((size_t)2 * Bn * 4) + al(4);
    size_t rec_one = al((size_t)E * 8);
    size_t rec_all = al((size_t)E * 8 * R);
    // Batched build needs rec+srec for all R ratings simultaneously.
    int batched = (ws_size >= base_need + 2 * rec_all + 65536) ? 1 : 0;
    size_t recsz = batched ? rec_all : rec_one;

    char* p = (char*)d_ws;
    auto carve = [&](size_t bytes) -> char* {
        char* q = p;
        p += (bytes + 255) & ~(size_t)255;
        return q;
    };
    float* out_acc = (float*)carve((size_t)N * 64 * 4);
    unsigned short* bufA = (unsigned short*)carve((size_t)N * 64 * 2);
    unsigned short* bufB = (unsigned short*)carve((size_t)N * 64 * 2);
    uint2* rec = (uint2*)carve(recsz);
    uint2* srec = (uint2*)carve(recsz);
    int* gcnt = (int*)carve((size_t)R * K * 4);
    int* bptr = (int*)carve((size_t)R * (K + 1) * 4);
    int* blockBase = (int*)carve((size_t)R * nb * K * 4);
    int* row_ptr = (int*)carve((size_t)R * (N + 1) * 4);
    float* c1_all = (float*)carve((size_t)R * 64 * 4);
    unsigned char* flag = (unsigned char*)carve((size_t)N);
    int* flist = (int*)carve((size_t)2 * Bn * 4);
    int* fcount = (int*)carve(4);

    uint64_t maskbits = compute_mask_bits();

    hipMemsetAsync(flag, 0, (size_t)N, stream);
    hipMemsetAsync(fcount, 0, 4, stream);
    hipMemsetAsync(gcnt, 0, (size_t)R * K * 4, stream);

    flag_kernel<<<(2 * Bn + 255) / 256, 256, 0, stream>>>(users, items, flag, Bn, U);
    flist_kernel<<<(N + 255) / 256, 256, 0, stream>>>(flag, flist, fcount, N);
    c1_kernel<<<R, 64, 0, stream>>>(rating_emb, W1, b1, c1_all);

    // Build pass A (batched over ratings) + per-rating scans
    dim3 cgrid(nb, R);
    bucket_count_kernel<<<cgrid, 1024, 0, stream>>>(rows, gcnt, blockBase, E, K, nb);
    bucket_scan_kernel<<<R, 256, 0, stream>>>(gcnt, bptr, K);

    if (batched) {
        dim3 sgrid(nb, R);
        if (K <= 512)
            bucket_scatter_kernel<<<sgrid, 1024, 0, stream>>>(
                rows, cols, vals, bptr, blockBase, rec, E, K,
                (long long)E, (long long)(K + 1), (long long)nb * K, (long long)E);
        else
            bucket_scatter_legacy<<<sgrid, 1024, 0, stream>>>(
                rows, cols, vals, bptr, blockBase, rec, E, K,
                (long long)E, (long long)(K + 1), (long long)nb * K, (long long)E);
        dim3 ogrid(K, R);
        bucket_sort_kernel<<<ogrid, 256, 0, stream>>>(
            rec, srec, bptr, row_ptr, K, N,
            (long long)E, (long long)(K + 1), (long long)(N + 1));
    }

    int spmm_blocks = (N + 3) / 4;
    int masked_blocks = (2 * Bn + 3) / 4;
    for (int r = 0; r < R; r++) {
        const int* bptr_r = bptr + (size_t)r * (K + 1);
        int* rp_r = row_ptr + (size_t)r * (N + 1);
        uint2* srec_r = batched ? (srec + (size_t)r * E) : srec;

        if (!batched) {
            dim3 sgrid(nb, 1);
            if (K <= 512)
                bucket_scatter_kernel<<<sgrid, 1024, 0, stream>>>(
                    rows + (size_t)r * E, cols + (size_t)r * E, vals + (size_t)r * E,
                    bptr_r, blockBase + (size_t)r * nb * K, rec, E, K, 0, 0, 0, 0);
            else
                bucket_scatter_legacy<<<sgrid, 1024, 0, stream>>>(
                    rows + (size_t)r * E, cols + (size_t)r * E, vals + (size_t)r * E,
                    bptr_r, blockBase + (size_t)r * nb * K, rec, E, K, 0, 0, 0, 0);
            dim3 ogrid(K, 1);
            bucket_sort_kernel<<<ogrid, 256, 0, stream>>>(
                rec, srec, bptr_r, rp_r, K, N, 0, 0, 0);
        }

        mlp_kernel<<<(N + 63) / 64, 256, 0, stream>>>(user_emb, item_emb, W1, W2,
                                                      c1_all, b2, bufA, out_acc,
                                                      flag, r, N, U, (r == 0) ? 1 : 0);

        spmm_kernel<<<spmm_blocks, 256, 0, stream>>>(bufA, bufB, out_acc, rp_r,
                                                     srec_r, flag, N);
        spmm_kernel<<<spmm_blocks, 256, 0, stream>>>(bufB, bufA, out_acc, rp_r,
                                                     srec_r, flag, N);
        spmm_masked_kernel<<<masked_blocks, 256, 0, stream>>>(bufA, out_acc, rp_r,
                                                              srec_r, maskbits,
                                                              flist, fcount);
    }

    float scale = 1.0f / (float)(R * R);
    dot_kernel<<<(Bn * 64 + 255) / 256, 256, 0, stream>>>(out_acc, users, items, out,
                                                          Bn, U, scale);
}

// Round 4
// 788.533 us; speedup vs baseline: 1.2703x; 1.0763x over previous
//
#include <hip/hip_runtime.h>
#include <hip/hip_bf16.h>
#include <cstdint>
#include <cstddef>

#define KEYSHIFT 20
#define COLMASK 0xFFFFFu
#define EPB 8192    // edges per count/scatter block (1024 threads x 8)
#define SUB 4096    // staged sub-chunk inside scatter (fits 54KB LDS)
#define BSHIFT 8    // 256 rows per bucket
#define NRB 256     // rows per bucket (1 << BSHIFT)
#define CCAP 3072   // LDS sort capacity per bucket (avg ~2560, max ~2750)

// bf16 pack/unpack: gathered operand is bf16 (halves the L2-miss fill
// traffic); all accumulation stays fp32.
__device__ __forceinline__ unsigned short f2bf(float f) {
    uint32_t u = __float_as_uint(f);
    u += ((u >> 16) & 1u) + 0x7fffu;   // RNE
    return (unsigned short)(u >> 16);
}
__device__ __forceinline__ float bf2f(unsigned short h) {
    return __uint_as_float(((uint32_t)h) << 16);
}

// ---------------------------------------------------------------------------
// Host-side reproduction of np.random.RandomState(2).permutation(64):
// MT19937 init_genrand(2), Fisher-Yates with numpy random_interval
// (mask+rejection). Mask bit d = (perm[d] >= 38).
// ---------------------------------------------------------------------------
static uint64_t compute_mask_bits() {
    uint32_t mt[624];
    mt[0] = 2u;
    for (int i = 1; i < 624; i++)
        mt[i] = 1812433253u * (mt[i - 1] ^ (mt[i - 1] >> 30)) + (uint32_t)i;
    int mti = 624;
    auto genrand = [&]() -> uint32_t {
        if (mti >= 624) {
            for (int k = 0; k < 624; k++) {
                uint32_t y = (mt[k] & 0x80000000u) | (mt[(k + 1) % 624] & 0x7fffffffu);
                mt[k] = mt[(k + 397) % 624] ^ (y >> 1) ^ ((y & 1u) ? 2567483615u : 0u);
            }
            mti = 0;
        }
        uint32_t y = mt[mti++];
        y ^= y >> 11;
        y ^= (y << 7) & 2636928640u;
        y ^= (y << 15) & 4022730752u;
        y ^= y >> 18;
        return y;
    };
    int arr[64];
    for (int i = 0; i < 64; i++) arr[i] = i;
    for (int i = 63; i >= 1; i--) {
        uint32_t mask = (uint32_t)i;
        mask |= mask >> 1; mask |= mask >> 2; mask |= mask >> 4;
        mask |= mask >> 8; mask |= mask >> 16;
        uint32_t v;
        do { v = genrand() & mask; } while (v > (uint32_t)i);
        int tmp = arr[i]; arr[i] = arr[v]; arr[v] = tmp;
    }
    uint64_t bits = 0;
    for (int d = 0; d < 64; d++)
        if (arr[d] >= 38) bits |= (1ull << d);
    return bits;
}

// ---------------------------------------------------------------------------
// Output-row flag set + compacted list (rows read by the final dot).
// ---------------------------------------------------------------------------
__global__ void flag_kernel(const int* __restrict__ users, const int* __restrict__ items,
                            unsigned char* __restrict__ flag, int B, int U) {
    int i = blockIdx.x * 256 + threadIdx.x;
    if (i < B) flag[users[i]] = 1;
    else if (i < 2 * B) flag[U + items[i - B]] = 1;
}

__global__ void flist_kernel(const unsigned char* __restrict__ flag,
                             int* __restrict__ flist, int* __restrict__ fcount, int n) {
    int i = blockIdx.x * 256 + threadIdx.x;
    if (i < n && flag[i]) {
        int p = atomicAdd(fcount, 1);
        flist[p] = i;
    }
}

// ---------------------------------------------------------------------------
// Per-rating constant c1[r][j] = b1[r][j] + sum_k e_r[k] * W1[r][64+k][j].
// ---------------------------------------------------------------------------
__global__ void c1_kernel(const float* __restrict__ rating_emb, const float* __restrict__ W1,
                          const float* __restrict__ b1, float* __restrict__ c1_all) {
    int r = blockIdx.x;
    int t = threadIdx.x;  // 64 threads
    const float* W1r = W1 + (size_t)r * (128 * 64);
    float acc = b1[r * 64 + t];
    for (int k = 0; k < 64; k++)
        acc += rating_emb[r * 64 + k] * W1r[(64 + k) * 64 + t];
    c1_all[r * 64 + t] = acc;
}

// ---------------------------------------------------------------------------
// Build pass A (batched over ratings): LDS histogram over K=ceil(N/256) row
// buckets, then ONE global atomicAdd per (block,bucket) to reserve a range.
// ---------------------------------------------------------------------------
__global__ __launch_bounds__(1024) void bucket_count_kernel(
    const int* __restrict__ rows, int* __restrict__ gcnt,
    int* __restrict__ blockBase, int E, int K, int nb) {
    __shared__ int hist[2048];
    int r = blockIdx.y, blk = blockIdx.x, t = threadIdx.x;
    for (int i = t; i < K; i += 1024) hist[i] = 0;
    __syncthreads();
    size_t base = (size_t)r * E + (size_t)blk * EPB;
    int cnt = E - blk * EPB;
    if (cnt > EPB) cnt = EPB;
    for (int k = t; k < cnt; k += 1024)
        atomicAdd(&hist[rows[base + k] >> BSHIFT], 1);
    __syncthreads();
    for (int i = t; i < K; i += 1024) {
        int c = hist[i];
        int bb = (c > 0) ? atomicAdd(&gcnt[r * K + i], c) : 0;
        blockBase[((size_t)r * nb + blk) * K + i] = bb;
    }
}

// ---------------------------------------------------------------------------
// Exclusive scan of K bucket counts -> bptr[K+1] per rating (grid.x = R).
// ---------------------------------------------------------------------------
__global__ void bucket_scan_kernel(const int* __restrict__ gcnt,
                                   int* __restrict__ bptr, int K) {
    __shared__ int sh[256];
    int r = blockIdx.x;
    int t = threadIdx.x;
    int base = t * 8;
    int v[8];
    int s = 0;
    #pragma unroll
    for (int j = 0; j < 8; j++) {
        int idx = base + j;
        v[j] = (idx < K) ? gcnt[r * K + idx] : 0;
        s += v[j];
    }
    sh[t] = s;
    __syncthreads();
    for (int off = 1; off < 256; off <<= 1) {
        int x = (t >= off) ? sh[t - off] : 0;
        __syncthreads();
        sh[t] += x;
        __syncthreads();
    }
    int run = sh[t] - s;
    #pragma unroll
    for (int j = 0; j < 8; j++) {
        int idx = base + j;
        if (idx <= K) bptr[r * (K + 1) + idx] = run;
        run += v[j];
    }
}

// ---------------------------------------------------------------------------
// Build pass B: LDS-STAGED scatter into bucket-grouped rec (K <= 512).
// Each 4096-edge sub-chunk is histogrammed, scanned, staged bucket-grouped
// in LDS with its final global address, then written out linearly.
// ---------------------------------------------------------------------------
__global__ __launch_bounds__(1024) void bucket_scatter_kernel(
    const int* __restrict__ rows, const int* __restrict__ cols,
    const float* __restrict__ vals, const int* __restrict__ bptr,
    const int* __restrict__ blockBase, uint2* __restrict__ rec,
    int E, int K, long long eStride, long long pStride,
    long long bbStride, long long rStride) {
    __shared__ uint2 staged[SUB];   // 32KB
    __shared__ int gaddr[SUB];      // 16KB final rec index per staged slot
    __shared__ int cursor[512];     // running global cursor per bucket
    __shared__ int lhist[512];      // per-subchunk count -> local base
    __shared__ int aux[512];        // scan scratch -> goff (=gbase-localbase)
    int r = blockIdx.y;
    const int* rows_r = rows + (size_t)r * eStride;
    const int* cols_r = cols + (size_t)r * eStride;
    const float* vals_r = vals + (size_t)r * eStride;
    const int* bptr_r = bptr + (size_t)r * pStride;
    const int* bb_r = blockBase + (size_t)r * bbStride;
    uint2* rec_r = rec + (size_t)r * rStride;
    int blk = blockIdx.x, t = threadIdx.x;
    if (t < 512)
        cursor[t] = (t < K) ? (bptr_r[t] + bb_r[(size_t)blk * K + t]) : 0;
    size_t base = (size_t)blk * EPB;
    int cnt = E - blk * EPB;
    if (cnt > EPB) cnt = EPB;
    for (int c0 = 0; c0 < cnt; c0 += SUB) {
        int scnt = cnt - c0;
        if (scnt > SUB) scnt = SUB;
        if (t < 512) lhist[t] = 0;
        __syncthreads();
        int bkt_[4], lpos_[4];
        uint2 rv_[4];
        #pragma unroll
        for (int q = 0; q < 4; q++) {
            int kk = (q << 10) + t;
            bkt_[q] = -1;
            if (kk < scnt) {
                size_t g = base + c0 + kk;
                int row = rows_r[g];
                int b = row >> BSHIFT;
                bkt_[q] = b;
                rv_[q] = make_uint2(((uint32_t)(row & (NRB - 1)) << KEYSHIFT) |
                                        (uint32_t)cols_r[g],
                                    __float_as_uint(vals_r[g]));
                lpos_[q] = atomicAdd(&lhist[b], 1);
            }
        }
        __syncthreads();
        int v = (t < 512) ? lhist[t] : 0;
        if (t < 512) aux[t] = v;
        __syncthreads();
        for (int off = 1; off < 512; off <<= 1) {
            int x = 0;
            if (t >= off && t < 512) x = aux[t - off];
            __syncthreads();
            if (t < 512) aux[t] += x;
            __syncthreads();
        }
        if (t < 512) {
            int ex = aux[t] - v;     // exclusive local base
            int gb = cursor[t];      // global base for this sub-chunk
            cursor[t] = gb + v;
            lhist[t] = ex;
            aux[t] = gb - ex;        // goff: gaddr = goff[b] + staged_idx
        }
        __syncthreads();
        #pragma unroll
        for (int q = 0; q < 4; q++) {
            if (bkt_[q] >= 0) {
                int sidx = lhist[bkt_[q]] + lpos_[q];
                staged[sidx] = rv_[q];
                gaddr[sidx] = aux[bkt_[q]] + sidx;
            }
        }
        __syncthreads();
        for (int i = t; i < scnt; i += 1024)
            rec_r[gaddr[i]] = staged[i];
        __syncthreads();
    }
}

// ---------------------------------------------------------------------------
// Build pass B legacy (direct scatter) — only used if K > 512.
// ---------------------------------------------------------------------------
__global__ __launch_bounds__(1024) void bucket_scatter_legacy(
    const int* __restrict__ rows, const int* __restrict__ cols,
    const float* __restrict__ vals, const int* __restrict__ bptr,
    const int* __restrict__ blockBase, uint2* __restrict__ rec,
    int E, int K, long long eStride, long long pStride,
    long long bbStride, long long rStride) {
    __shared__ int cursor[2048];
    int r = blockIdx.y;
    const int* rows_r = rows + (size_t)r * eStride;
    const int* cols_r = cols + (size_t)r * eStride;
    const float* vals_r = vals + (size_t)r * eStride;
    const int* bptr_r = bptr + (size_t)r * pStride;
    const int* bb_r = blockBase + (size_t)r * bbStride;
    uint2* rec_r = rec + (size_t)r * rStride;
    int blk = blockIdx.x, t = threadIdx.x;
    for (int i = t; i < K; i += 1024)
        cursor[i] = bptr_r[i] + bb_r[(size_t)blk * K + i];
    __syncthreads();
    size_t base = (size_t)blk * EPB;
    int cnt = E - blk * EPB;
    if (cnt > EPB) cnt = EPB;
    for (int k = t; k < cnt; k += 1024) {
        int row = rows_r[base + k];
        int b = row >> BSHIFT;
        int pos = atomicAdd(&cursor[b], 1);
        uint32_t key = ((uint32_t)(row & (NRB - 1)) << KEYSHIFT) | (uint32_t)cols_r[base + k];
        rec_r[pos] = make_uint2(key, __float_as_uint(vals_r[base + k]));
    }
}

// ---------------------------------------------------------------------------
// Build pass C: per-bucket counting sort by rel-row, FULLY IN LDS; srec
// written as one dense coalesced stream. Emits row_ptr.
// ---------------------------------------------------------------------------
__global__ __launch_bounds__(256) void bucket_sort_kernel(
    const uint2* __restrict__ rec, uint2* __restrict__ srec,
    const int* __restrict__ bptr, int* __restrict__ rp, int K, int N,
    long long rStride, long long pStride, long long rpStride) {
    __shared__ uint2 staged[CCAP];  // 24KB
    __shared__ int hist[NRB];
    __shared__ int excl[NRB];
    int r = blockIdx.y;
    const uint2* rec_r = rec + (size_t)r * rStride;
    uint2* srec_r = srec + (size_t)r * rStride;
    const int* bptr_r = bptr + (size_t)r * pStride;
    int* rp_r = rp + (size_t)r * rpStride;
    int b = blockIdx.x;
    int t = threadIdx.x;          // 256 threads == NRB
    hist[t] = 0;
    __syncthreads();
    int start = bptr_r[b], end = bptr_r[b + 1];
    int m = end - start;
    for (int e = start + t; e < end; e += 256)
        atomicAdd(&hist[rec_r[e].x >> KEYSHIFT], 1);
    __syncthreads();
    int v = hist[t];
    excl[t] = v;
    __syncthreads();
    for (int off = 1; off < 256; off <<= 1) {
        int x = (t >= off) ? excl[t - off] : 0;
        __syncthreads();
        excl[t] += x;
        __syncthreads();
    }
    int ex = excl[t] - v;
    excl[t] = ex;                 // own-slot overwrite, no cross-read yet
    hist[t] = 0;                  // reuse as cursors
    int row = b * NRB + t;
    if (row < N) rp_r[row] = start + ex;
    if (b == K - 1 && t == 0) rp_r[N] = bptr_r[K];
    __syncthreads();
    if (m <= CCAP) {
        for (int e = start + t; e < end; e += 256) {
            uint2 rr = rec_r[e];
            int rel = (int)(rr.x >> KEYSHIFT);
            int pos = excl[rel] + atomicAdd(&hist[rel], 1);
            staged[pos] = rr;
        }
        __syncthreads();
        for (int i = t; i < m; i += 256)
            srec_r[start + i] = staged[i];
    } else {
        for (int e = start + t; e < end; e += 256) {
            uint2 rr = rec_r[e];
            int rel = (int)(rr.x >> KEYSHIFT);
            int pos = start + excl[rel] + atomicAdd(&hist[rel], 1);
            srec_r[pos] = rr;
        }
    }
}

// ---------------------------------------------------------------------------
// Per-rating MLP: h = leaky_relu(x @ W1a + c1) @ W2 + b2
// prev is written as bf16 (gather operand); out_acc stays fp32:
// init ? store : RMW-add (init at r=0 replaces the 25.6MB memset).
// ---------------------------------------------------------------------------
__global__ __launch_bounds__(256) void mlp_kernel(
    const float* __restrict__ user_emb, const float* __restrict__ item_emb,
    const float* __restrict__ W1, const float* __restrict__ W2,
    const float* __restrict__ c1_all, const float* __restrict__ b2,
    unsigned short* __restrict__ prev, float* __restrict__ out_acc,
    const unsigned char* __restrict__ flag, int r, int n_rows, int U, int init) {
    __shared__ float sW[64 * 64];   // [k][j], linear
    __shared__ float sX[64 * 64];   // [k][i], group-swizzled; reused for T
    __shared__ float sc1[64];
    __shared__ float sb2v[64];

    int t = threadIdx.x;
    int row0 = blockIdx.x * 64;
    const float* W1r = W1 + (size_t)r * (128 * 64);
    const float* W2r = W2 + (size_t)r * (64 * 64);

    #pragma unroll
    for (int q = 0; q < 4; q++) {
        int f = t + 256 * q;
        int k = f >> 4, c = (f & 15) * 4;
        *(float4*)(sW + k * 64 + c) = *(const float4*)(W1r + k * 64 + c);
    }
    #pragma unroll
    for (int q = 0; q < 4; q++) {
        int f = t + 256 * q;
        int i = f & 63;
        int c = (f >> 6) * 4;
        int nrow = row0 + i;
        float4 xv = make_float4(0.f, 0.f, 0.f, 0.f);
        if (nrow < n_rows) {
            const float* src = (nrow < U) ? (user_emb + (size_t)nrow * 64)
                                          : (item_emb + (size_t)(nrow - U) * 64);
            xv = *(const float4*)(src + c);
        }
        int gi = i >> 2, w = i & 3;
        sX[(c + 0) * 64 + 4 * (gi ^ ((c + 0) & 15)) + w] = xv.x;
        sX[(c + 1) * 64 + 4 * (gi ^ ((c + 1) & 15)) + w] = xv.y;
        sX[(c + 2) * 64 + 4 * (gi ^ ((c + 2) & 15)) + w] = xv.z;
        sX[(c + 3) * 64 + 4 * (gi ^ ((c + 3) & 15)) + w] = xv.w;
    }
    if (t < 64) sc1[t] = c1_all[r * 64 + t];
    else if (t < 128) sb2v[t - 64] = b2[r * 64 + (t - 64)];
    __syncthreads();

    int gi = t & 15;
    int i0 = gi * 4, j0 = (t >> 4) * 4;
    float acc[4][4];
    #pragma unroll
    for (int a = 0; a < 4; a++)
        #pragma unroll
        for (int b = 0; b < 4; b++) acc[a][b] = sc1[j0 + b];
    for (int k = 0; k < 64; k++) {
        float4 xv = *(const float4*)(sX + k * 64 + 4 * (gi ^ (k & 15)));
        float4 wv = *(const float4*)(sW + k * 64 + j0);
        float xs[4] = {xv.x, xv.y, xv.z, xv.w};
        float ws[4] = {wv.x, wv.y, wv.z, wv.w};
        #pragma unroll
        for (int a = 0; a < 4; a++)
            #pragma unroll
            for (int b = 0; b < 4; b++) acc[a][b] += xs[a] * ws[b];
    }
    __syncthreads();

    #pragma unroll
    for (int b = 0; b < 4; b++) {
        int k = j0 + b;
        float4 tv;
        tv.x = (acc[0][b] >= 0.f) ? acc[0][b] : 0.01f * acc[0][b];
        tv.y = (acc[1][b] >= 0.f) ? acc[1][b] : 0.01f * acc[1][b];
        tv.z = (acc[2][b] >= 0.f) ? acc[2][b] : 0.01f * acc[2][b];
        tv.w = (acc[3][b] >= 0.f) ? acc[3][b] : 0.01f * acc[3][b];
        *(float4*)(sX + k * 64 + 4 * (gi ^ (k & 15))) = tv;
    }
    #pragma unroll
    for (int q = 0; q < 4; q++) {
        int f = t + 256 * q;
        int k = f >> 4, c = (f & 15) * 4;
        *(float4*)(sW + k * 64 + c) = *(const float4*)(W2r + k * 64 + c);
    }
    __syncthreads();

    #pragma unroll
    for (int a = 0; a < 4; a++)
        #pragma unroll
        for (int b = 0; b < 4; b++) acc[a][b] = sb2v[j0 + b];
    for (int k = 0; k < 64; k++) {
        float4 xv = *(const float4*)(sX + k * 64 + 4 * (gi ^ (k & 15)));
        float4 wv = *(const float4*)(sW + k * 64 + j0);
        float xs[4] = {xv.x, xv.y, xv.z, xv.w};
        float ws[4] = {wv.x, wv.y, wv.z, wv.w};
        #pragma unroll
        for (int a = 0; a < 4; a++)
            #pragma unroll
            for (int b = 0; b < 4; b++) acc[a][b] += xs[a] * ws[b];
    }
    #pragma unroll
    for (int a = 0; a < 4; a++) {
        int nrow = row0 + i0 + a;
        if (nrow < n_rows) {
            float4 hv = make_float4(acc[a][0], acc[a][1], acc[a][2], acc[a][3]);
            ushort4 hb;
            hb.x = f2bf(hv.x); hb.y = f2bf(hv.y);
            hb.z = f2bf(hv.z); hb.w = f2bf(hv.w);
            *(ushort4*)(prev + (size_t)nrow * 64 + j0) = hb;
            if (flag[nrow]) {
                float* o = out_acc + (size_t)nrow * 64 + j0;
                if (init) {
                    *(float4*)o = hv;
                } else {
                    float4 ov = *(const float4*)o;
                    ov.x += hv.x; ov.y += hv.y; ov.z += hv.z; ov.w += hv.w;
                    *(float4*)o = ov;
                }
            }
        }
    }
}

// ---------------------------------------------------------------------------
// Gather-SpMM (layers 0/1): wave = 1 row; 4 edge-groups x 16 lanes.
// R13->R15 lesson: at the bf16 byte count the kernel is LATENCY-bound
// (1.35 TB/s << 2.5 TB/s fill wall, VALU 39%). Batch 4 edges per sub per
// iteration: 4 rec loads issued back-to-back, then 4 gathers — collapses
// ~4-6 dependent memory legs per row into ~2. Invalid slots clamp to
// rec[ew] (same line as slot 0 -> L1 hit) with v=0.
// ---------------------------------------------------------------------------
__global__ __launch_bounds__(256) void spmm_kernel(
    const unsigned short* __restrict__ prev, unsigned short* __restrict__ next,
    float* __restrict__ out_acc, const int* __restrict__ rp,
    const uint2* __restrict__ rec, const unsigned char* __restrict__ flag, int n) {
    int wave = (int)((blockIdx.x * (unsigned)blockDim.x + threadIdx.x) >> 6);
    int lane = threadIdx.x & 63;
    if (wave >= n) return;
    int sub = lane >> 4;      // edge group 0..3
    int dl = lane & 15;       // dims [dl*4, dl*4+4)
    int s = rp[wave], e2 = rp[wave + 1];
    float ax = 0.f, ay = 0.f, az = 0.f, aw = 0.f;
    for (int ew = s + sub; ew < e2; ew += 16) {
        int i1 = ew + 4, i2 = ew + 8, i3 = ew + 12;
        uint2 r0 = rec[ew];
        uint2 r1 = rec[i1 < e2 ? i1 : ew];
        uint2 r2 = rec[i2 < e2 ? i2 : ew];
        uint2 r3 = rec[i3 < e2 ? i3 : ew];
        float v0 = __uint_as_float(r0.y);
        float v1 = (i1 < e2) ? __uint_as_float(r1.y) : 0.f;
        float v2 = (i2 < e2) ? __uint_as_float(r2.y) : 0.f;
        float v3 = (i3 < e2) ? __uint_as_float(r3.y) : 0.f;
        ushort4 q0 = *(const ushort4*)(prev + (size_t)(r0.x & COLMASK) * 64 + dl * 4);
        ushort4 q1 = *(const ushort4*)(prev + (size_t)(r1.x & COLMASK) * 64 + dl * 4);
        ushort4 q2 = *(const ushort4*)(prev + (size_t)(r2.x & COLMASK) * 64 + dl * 4);
        ushort4 q3 = *(const ushort4*)(prev + (size_t)(r3.x & COLMASK) * 64 + dl * 4);
        ax += v0 * bf2f(q0.x) + v1 * bf2f(q1.x) + v2 * bf2f(q2.x) + v3 * bf2f(q3.x);
        ay += v0 * bf2f(q0.y) + v1 * bf2f(q1.y) + v2 * bf2f(q2.y) + v3 * bf2f(q3.y);
        az += v0 * bf2f(q0.z) + v1 * bf2f(q1.z) + v2 * bf2f(q2.z) + v3 * bf2f(q3.z);
        aw += v0 * bf2f(q0.w) + v1 * bf2f(q1.w) + v2 * bf2f(q2.w) + v3 * bf2f(q3.w);
    }
    ax += __shfl_xor(ax, 16); ay += __shfl_xor(ay, 16);
    az += __shfl_xor(az, 16); aw += __shfl_xor(aw, 16);
    ax += __shfl_xor(ax, 32); ay += __shfl_xor(ay, 32);
    az += __shfl_xor(az, 32); aw += __shfl_xor(aw, 32);
    if (sub == 0) {
        ushort4 nv;
        nv.x = f2bf(ax); nv.y = f2bf(ay); nv.z = f2bf(az); nv.w = f2bf(aw);
        *(ushort4*)(next + (size_t)wave * 64 + dl * 4) = nv;
    } else if (sub == 1 && flag[wave]) {
        float* o = out_acc + (size_t)wave * 64 + dl * 4;
        float4 ov = *(const float4*)o;
        ov.x += ax; ov.y += ay; ov.z += az; ov.w += aw;
        *(float4*)o = ov;
    }
}

// ---------------------------------------------------------------------------
// Layer-2 (masked) SpMM: only rows in flist. Same batched-edge form.
// ---------------------------------------------------------------------------
__global__ __launch_bounds__(256) void spmm_masked_kernel(
    const unsigned short* __restrict__ prev, float* __restrict__ out_acc,
    const int* __restrict__ rp, const uint2* __restrict__ rec,
    unsigned long long maskbits, const int* __restrict__ flist,
    const int* __restrict__ fcount) {
    int w = (int)((blockIdx.x * (unsigned)blockDim.x + threadIdx.x) >> 6);
    int lane = threadIdx.x & 63;
    if (w >= *fcount) return;
    int sub = lane >> 4;
    int dl = lane & 15;
    int row = flist[w];
    int s = rp[row], e2 = rp[row + 1];
    float ax = 0.f, ay = 0.f, az = 0.f, aw = 0.f;
    for (int ew = s + sub; ew < e2; ew += 16) {
        int i1 = ew + 4, i2 = ew + 8, i3 = ew + 12;
        uint2 r0 = rec[ew];
        uint2 r1 = rec[i1 < e2 ? i1 : ew];
        uint2 r2 = rec[i2 < e2 ? i2 : ew];
        uint2 r3 = rec[i3 < e2 ? i3 : ew];
        float v0 = __uint_as_float(r0.y);
        float v1 = (i1 < e2) ? __uint_as_float(r1.y) : 0.f;
        float v2 = (i2 < e2) ? __uint_as_float(r2.y) : 0.f;
        float v3 = (i3 < e2) ? __uint_as_float(r3.y) : 0.f;
        ushort4 q0 = *(const ushort4*)(prev + (size_t)(r0.x & COLMASK) * 64 + dl * 4);
        ushort4 q1 = *(const ushort4*)(prev + (size_t)(r1.x & COLMASK) * 64 + dl * 4);
        ushort4 q2 = *(const ushort4*)(prev + (size_t)(r2.x & COLMASK) * 64 + dl * 4);
        ushort4 q3 = *(const ushort4*)(prev + (size_t)(r3.x & COLMASK) * 64 + dl * 4);
        ax += v0 * bf2f(q0.x) + v1 * bf2f(q1.x) + v2 * bf2f(q2.x) + v3 * bf2f(q3.x);
        ay += v0 * bf2f(q0.y) + v1 * bf2f(q1.y) + v2 * bf2f(q2.y) + v3 * bf2f(q3.y);
        az += v0 * bf2f(q0.z) + v1 * bf2f(q1.z) + v2 * bf2f(q2.z) + v3 * bf2f(q3.z);
        aw += v0 * bf2f(q0.w) + v1 * bf2f(q1.w) + v2 * bf2f(q2.w) + v3 * bf2f(q3.w);
    }
    ax += __shfl_xor(ax, 16); ay += __shfl_xor(ay, 16);
    az += __shfl_xor(az, 16); aw += __shfl_xor(aw, 16);
    ax += __shfl_xor(ax, 32); ay += __shfl_xor(ay, 32);
    az += __shfl_xor(az, 32); aw += __shfl_xor(aw, 32);
    if (sub == 0) {
        ushort4 pq = *(const ushort4*)(prev + (size_t)row * 64 + dl * 4);
        float px = bf2f(pq.x), py = bf2f(pq.y), pz = bf2f(pq.z), pw = bf2f(pq.w);
        float rx = ((maskbits >> (dl * 4 + 0)) & 1ull) ? ax : px;
        float ry = ((maskbits >> (dl * 4 + 1)) & 1ull) ? ay : py;
        float rz = ((maskbits >> (dl * 4 + 2)) & 1ull) ? az : pz;
        float rw = ((maskbits >> (dl * 4 + 3)) & 1ull) ? aw : pw;
        float* o = out_acc + (size_t)row * 64 + dl * 4;
        float4 ov = *(const float4*)o;
        ov.x += rx; ov.y += ry; ov.z += rz; ov.w += rw;
        *(float4*)o = ov;
    }
}

// ---------------------------------------------------------------------------
// Final: out[b] = (1/R^2) * dot(out_acc[users[b]], out_acc[U+items[b]])
// ---------------------------------------------------------------------------
__global__ __launch_bounds__(256) void dot_kernel(
    const float* __restrict__ out_acc, const int* __restrict__ users,
    const int* __restrict__ items, float* __restrict__ out,
    int Bn, int U, float scale) {
    int w = (int)((blockIdx.x * (unsigned)blockDim.x + threadIdx.x) >> 6);
    int lane = threadIdx.x & 63;
    if (w >= Bn) return;
    int u = users[w], it = items[w];
    float a = out_acc[(size_t)u * 64 + lane];
    float c = out_acc[((size_t)(U + it)) * 64 + lane];
    float p = a * c;
    #pragma unroll
    for (int off = 32; off > 0; off >>= 1) p += __shfl_down(p, off);
    if (lane == 0) out[w] = p * scale;
}

// ---------------------------------------------------------------------------
extern "C" void kernel_launch(void* const* d_in, const int* in_sizes, int n_in,
                              void* d_out, int out_size, void* d_ws, size_t ws_size,
                              hipStream_t stream) {
    const int* users = (const int*)d_in[0];
    const int* items = (const int*)d_in[1];
    const float* user_emb = (const float*)d_in[2];
    const float* item_emb = (const float*)d_in[3];
    const float* rating_emb = (const float*)d_in[4];
    const float* W1 = (const float*)d_in[5];
    const float* b1 = (const float*)d_in[6];
    const float* W2 = (const float*)d_in[7];
    const float* b2 = (const float*)d_in[8];
    const int* rows = (const int*)d_in[9];
    const int* cols = (const int*)d_in[10];
    const float* vals = (const float*)d_in[11];
    float* out = (float*)d_out;

    const int Dd = 64;
    int U = in_sizes[2] / Dd;
    int I = in_sizes[3] / Dd;
    int R = in_sizes[4] / Dd;
    int N = U + I;
    int E = in_sizes[9] / R;
    int Bn = in_sizes[0];
    int K = (N + NRB - 1) / NRB;    // 256-row buckets; K+1 <= 2048
    int nb = (E + EPB - 1) / EPB;   // count/scatter blocks per rating

    auto al = [](size_t b) { return (b + 255) & ~(size_t)255; };
    size_t base_need = al((size_t)N * 64 * 4) + 2 * al((size_t)N * 64 * 2)
        + al((size_t)R * K * 4)
        + al((size_t)R * (K + 1) * 4) + al((size_t)R * nb * K * 4)
        + al((size_t)R * (N + 1) * 4) + al((size_t)R * 64 * 4)
        + al((size_t)N) + al((size_t)2 * Bn * 4) + al(4);
    size_t rec_one = al((size_t)E * 8);
    size_t rec_all = al((size_t)E * 8 * R);
    // Batched build needs rec+srec for all R ratings simultaneously.
    int batched = (ws_size >= base_need + 2 * rec_all + 65536) ? 1 : 0;
    size_t recsz = batched ? rec_all : rec_one;

    char* p = (char*)d_ws;
    auto carve = [&](size_t bytes) -> char* {
        char* q = p;
        p += (bytes + 255) & ~(size_t)255;
        return q;
    };
    float* out_acc = (float*)carve((size_t)N * 64 * 4);
    unsigned short* bufA = (unsigned short*)carve((size_t)N * 64 * 2);
    unsigned short* bufB = (unsigned short*)carve((size_t)N * 64 * 2);
    uint2* rec = (uint2*)carve(recsz);
    uint2* srec = (uint2*)carve(recsz);
    int* gcnt = (int*)carve((size_t)R * K * 4);
    int* bptr = (int*)carve((size_t)R * (K + 1) * 4);
    int* blockBase = (int*)carve((size_t)R * nb * K * 4);
    int* row_ptr = (int*)carve((size_t)R * (N + 1) * 4);
    float* c1_all = (float*)carve((size_t)R * 64 * 4);
    unsigned char* flag = (unsigned char*)carve((size_t)N);
    int* flist = (int*)carve((size_t)2 * Bn * 4);
    int* fcount = (int*)carve(4);

    uint64_t maskbits = compute_mask_bits();

    hipMemsetAsync(flag, 0, (size_t)N, stream);
    hipMemsetAsync(fcount, 0, 4, stream);
    hipMemsetAsync(gcnt, 0, (size_t)R * K * 4, stream);

    flag_kernel<<<(2 * Bn + 255) / 256, 256, 0, stream>>>(users, items, flag, Bn, U);
    flist_kernel<<<(N + 255) / 256, 256, 0, stream>>>(flag, flist, fcount, N);
    c1_kernel<<<R, 64, 0, stream>>>(rating_emb, W1, b1, c1_all);

    // Build pass A (batched over ratings) + per-rating scans
    dim3 cgrid(nb, R);
    bucket_count_kernel<<<cgrid, 1024, 0, stream>>>(rows, gcnt, blockBase, E, K, nb);
    bucket_scan_kernel<<<R, 256, 0, stream>>>(gcnt, bptr, K);

    if (batched) {
        dim3 sgrid(nb, R);
        if (K <= 512)
            bucket_scatter_kernel<<<sgrid, 1024, 0, stream>>>(
                rows, cols, vals, bptr, blockBase, rec, E, K,
                (long long)E, (long long)(K + 1), (long long)nb * K, (long long)E);
        else
            bucket_scatter_legacy<<<sgrid, 1024, 0, stream>>>(
                rows, cols, vals, bptr, blockBase, rec, E, K,
                (long long)E, (long long)(K + 1), (long long)nb * K, (long long)E);
        dim3 ogrid(K, R);
        bucket_sort_kernel<<<ogrid, 256, 0, stream>>>(
            rec, srec, bptr, row_ptr, K, N,
            (long long)E, (long long)(K + 1), (long long)(N + 1));
    }

    int spmm_blocks = (N + 3) / 4;
    int masked_blocks = (2 * Bn + 3) / 4;
    for (int r = 0; r < R; r++) {
        const int* bptr_r = bptr + (size_t)r * (K + 1);
        int* rp_r = row_ptr + (size_t)r * (N + 1);
        uint2* srec_r = batched ? (srec + (size_t)r * E) : srec;

        if (!batched) {
            dim3 sgrid(nb, 1);
            if (K <= 512)
                bucket_scatter_kernel<<<sgrid, 1024, 0, stream>>>(
                    rows + (size_t)r * E, cols + (size_t)r * E, vals + (size_t)r * E,
                    bptr_r, blockBase + (size_t)r * nb * K, rec, E, K, 0, 0, 0, 0);
            else
                bucket_scatter_legacy<<<sgrid, 1024, 0, stream>>>(
                    rows + (size_t)r * E, cols + (size_t)r * E, vals + (size_t)r * E,
                    bptr_r, blockBase + (size_t)r * nb * K, rec, E, K, 0, 0, 0, 0);
            dim3 ogrid(K, 1);
            bucket_sort_kernel<<<ogrid, 256, 0, stream>>>(
                rec, srec, bptr_r, rp_r, K, N, 0, 0, 0);
        }

        mlp_kernel<<<(N + 63) / 64, 256, 0, stream>>>(user_emb, item_emb, W1, W2,
                                                      c1_all, b2, bufA, out_acc,
                                                      flag, r, N, U, (r == 0) ? 1 : 0);

        spmm_kernel<<<spmm_blocks, 256, 0, stream>>>(bufA, bufB, out_acc, rp_r,
                                                     srec_r, flag, N);
        spmm_kernel<<<spmm_blocks, 256, 0, stream>>>(bufB, bufA, out_acc, rp_r,
                                                     srec_r, flag, N);
        spmm_masked_kernel<<<masked_blocks, 256, 0, stream>>>(bufA, out_acc, rp_r,
                                                              srec_r, maskbits,
                                                              flist, fcount);
    }

    float scale = 1.0f / (float)(R * R);
    dot_kernel<<<(Bn * 64 + 255) / 256, 256, 0, stream>>>(out_acc, users, items, out,
                                                          Bn, U, scale);
}